// Round 1
// baseline (503.230 us; speedup 1.0000x reference)
//
#include <hip/hip_runtime.h>

// Problem constants
#define BB    8
#define HH    56
#define WW    56
#define DIMI  96
#define E3    576    // 3*192
#define DIMO  192
#define NH    3
#define HD    64
#define NK    3136   // 56*56 keys per (b,h)
#define NQ    784    // 28*28 queries per (b,h)
#define M1    25088  // B*H*W
#define M2    6272   // B*NQ

// ---------------------------------------------------------------------------
// Generic tiled fp32 GEMM: C[M][LDB] = A[M][K] @ B[K][LDB](cols bn..bn+63) + bias
// block = 256 threads, tile 32 rows x 64 cols, K staged in chunks of 96.
// ---------------------------------------------------------------------------
template<int K, int LDB>
__launch_bounds__(256)
__global__ void gemm_kernel(const float* __restrict__ A,
                            const float* __restrict__ B,
                            const float* __restrict__ bias,
                            float* __restrict__ C) {
    constexpr int KT = 96;
    __shared__ float As[32][KT + 4];   // +4 pad: keeps 16B align, breaks bank stride
    __shared__ float Bs[KT][64];

    const int tid = threadIdx.x;
    const int bm = blockIdx.y * 32;
    const int bn = blockIdx.x * 64;
    const int tx = tid & 15;     // 16 col-groups (float4)
    const int ty = tid >> 4;     // 16 row threads; each does rows ty, ty+16

    float4 acc0 = {0.f, 0.f, 0.f, 0.f};
    float4 acc1 = {0.f, 0.f, 0.f, 0.f};

    for (int k0 = 0; k0 < K; k0 += KT) {
        // Load A tile: 32 x 96 floats = 768 float4, 3 per thread
#pragma unroll
        for (int i = 0; i < 3; ++i) {
            int f = tid + i * 256;
            int r = f / 24, c = f % 24;
            float4 v = ((const float4*)A)[(size_t)(bm + r) * (K / 4) + (k0 / 4) + c];
            ((float4*)&As[r][0])[c] = v;
        }
        // Load B tile: 96 x 64 floats = 1536 float4, 6 per thread
#pragma unroll
        for (int i = 0; i < 6; ++i) {
            int f = tid + i * 256;
            int r = f >> 4, c = f & 15;
            float4 v = ((const float4*)B)[(size_t)(k0 + r) * (LDB / 4) + (bn >> 2) + c];
            ((float4*)&Bs[r][0])[c] = v;
        }
        __syncthreads();

#pragma unroll 8
        for (int k = 0; k < KT; ++k) {
            float a0 = As[ty][k];
            float a1 = As[ty + 16][k];
            float4 b = ((const float4*)&Bs[k][0])[tx];
            acc0.x = fmaf(a0, b.x, acc0.x);
            acc0.y = fmaf(a0, b.y, acc0.y);
            acc0.z = fmaf(a0, b.z, acc0.z);
            acc0.w = fmaf(a0, b.w, acc0.w);
            acc1.x = fmaf(a1, b.x, acc1.x);
            acc1.y = fmaf(a1, b.y, acc1.y);
            acc1.z = fmaf(a1, b.z, acc1.z);
            acc1.w = fmaf(a1, b.w, acc1.w);
        }
        __syncthreads();
    }

    float4 bb = ((const float4*)bias)[(bn >> 2) + tx];
    acc0.x += bb.x; acc0.y += bb.y; acc0.z += bb.z; acc0.w += bb.w;
    acc1.x += bb.x; acc1.y += bb.y; acc1.z += bb.z; acc1.w += bb.w;

    ((float4*)C)[(size_t)(bm + ty) * (LDB / 4) + (bn >> 2) + tx] = acc0;
    ((float4*)C)[(size_t)(bm + ty + 16) * (LDB / 4) + (bn >> 2) + tx] = acc1;
}

// ---------------------------------------------------------------------------
// Q maxpool 2x2 + 1/sqrt(64) scale.
// QKV layout: [b*3136 + y*56 + x][576], q section cols 0..191 (col = h*64+d)
// Qp layout:  [(b*3+h)*784 + q][64]
// ---------------------------------------------------------------------------
__global__ void qpool_kernel(const float* __restrict__ QKV, float* __restrict__ Qp) {
    int idx = blockIdx.x * 256 + threadIdx.x;
    if (idx >= BB * NH * NQ * HD) return;
    int d  = idx & 63;
    int q  = (idx >> 6) % NQ;
    int bh = idx / (64 * NQ);
    int b = bh / NH, h = bh % NH;
    int hq = q / 28, wq = q % 28;
    int col = h * 64 + d;
    const float* base = QKV + (size_t)b * NK * E3 + col;
    int r0 = (2 * hq) * 56 + 2 * wq;
    float m = base[(size_t)r0 * E3];
    m = fmaxf(m, base[(size_t)(r0 + 1) * E3]);
    m = fmaxf(m, base[(size_t)(r0 + 56) * E3]);
    m = fmaxf(m, base[(size_t)(r0 + 57) * E3]);
    Qp[idx] = m * 0.125f;
}

// ---------------------------------------------------------------------------
// Attention: per block = (q-tile of 32, bh pair). Q row in registers,
// K/V tiles in LDS, exp-without-max-shift (logits bounded), single pass.
// Output AO[(b*784+q)*192 + h*64 + d]
// ---------------------------------------------------------------------------
__launch_bounds__(256)
__global__ void attn_kernel(const float* __restrict__ QKV,
                            const float* __restrict__ Qp,
                            float* __restrict__ AO) {
    __shared__ float Ks[32][68];
    __shared__ float Vs[32][68];
    __shared__ float Ps[32][33];

    const int bh = blockIdx.y;          // 0..23
    const int b = bh / NH, h = bh % NH;
    const int qt = blockIdx.x * 32;     // 0..768
    const int tid = threadIdx.x;

    // S-phase mapping
    const int qi = tid & 31;
    const int kg = tid >> 5;            // 0..7, covers keys kg*4..kg*4+3
    // PV-phase mapping
    const int oqi = tid >> 3;           // 0..31
    const int od  = (tid & 7) * 8;      // d offset, 8 floats

    // Load this thread's Q row (64 floats) into registers
    float4 qreg[16];
    {
        int q = qt + qi;
        if (q < NQ) {
            const float4* qp = (const float4*)(Qp + ((size_t)bh * NQ + q) * HD);
#pragma unroll
            for (int c = 0; c < 16; ++c) qreg[c] = qp[c];
        } else {
#pragma unroll
            for (int c = 0; c < 16; ++c) qreg[c] = make_float4(0.f, 0.f, 0.f, 0.f);
        }
    }

    float oacc[8];
#pragma unroll
    for (int i = 0; i < 8; ++i) oacc[i] = 0.f;
    float den = 0.f;

    const float* Kbase = QKV + (size_t)b * NK * E3 + DIMO + h * 64;   // k section
    const float* Vbase = Kbase + DIMO;                                // v section

    for (int kt = 0; kt < NK; kt += 32) {
        // Stage K,V tiles (32 x 64 each): 512 float4 each, 2 per thread
#pragma unroll
        for (int i = 0; i < 2; ++i) {
            int f = tid + i * 256;
            int r = f >> 4, c = f & 15;
            const float4* kp = (const float4*)(Kbase + (size_t)(kt + r) * E3);
            const float4* vp = (const float4*)(Vbase + (size_t)(kt + r) * E3);
            ((float4*)&Ks[r][0])[c] = kp[c];
            ((float4*)&Vs[r][0])[c] = vp[c];
        }
        __syncthreads();

        // S[qi][kg*4+j] = Q[qi] . K[kg*4+j]; P = exp(S) (no max shift: |S| < 1)
#pragma unroll
        for (int j = 0; j < 4; ++j) {
            const float4* kr = (const float4*)&Ks[kg * 4 + j][0];
            float acc = 0.f;
#pragma unroll
            for (int c = 0; c < 16; ++c) {
                float4 k4 = kr[c];
                float4 q4 = qreg[c];
                acc = fmaf(q4.x, k4.x, acc);
                acc = fmaf(q4.y, k4.y, acc);
                acc = fmaf(q4.z, k4.z, acc);
                acc = fmaf(q4.w, k4.w, acc);
            }
            Ps[qi][kg * 4 + j] = __expf(acc);
        }
        __syncthreads();

        // O[oqi][od..od+7] += sum_kj P[oqi][kj] * V[kj][od..]
#pragma unroll
        for (int kj = 0; kj < 32; ++kj) {
            float p = Ps[oqi][kj];
            den += p;
            const float4* vr = (const float4*)&Vs[kj][od];
            float4 va = vr[0], vb = vr[1];
            oacc[0] = fmaf(p, va.x, oacc[0]);
            oacc[1] = fmaf(p, va.y, oacc[1]);
            oacc[2] = fmaf(p, va.z, oacc[2]);
            oacc[3] = fmaf(p, va.w, oacc[3]);
            oacc[4] = fmaf(p, vb.x, oacc[4]);
            oacc[5] = fmaf(p, vb.y, oacc[5]);
            oacc[6] = fmaf(p, vb.z, oacc[6]);
            oacc[7] = fmaf(p, vb.w, oacc[7]);
        }
        __syncthreads();
    }

    int q = qt + oqi;
    if (q < NQ) {
        float inv = 1.0f / den;
        float* op = AO + ((size_t)b * NQ + q) * DIMO + h * 64 + od;
        float4 o0 = { oacc[0] * inv, oacc[1] * inv, oacc[2] * inv, oacc[3] * inv };
        float4 o1 = { oacc[4] * inv, oacc[5] * inv, oacc[6] * inv, oacc[7] * inv };
        ((float4*)op)[0] = o0;
        ((float4*)op)[1] = o1;
    }
}

// ---------------------------------------------------------------------------
extern "C" void kernel_launch(void* const* d_in, const int* in_sizes, int n_in,
                              void* d_out, int out_size, void* d_ws, size_t ws_size,
                              hipStream_t stream) {
    const float* x     = (const float*)d_in[0];
    const float* Wqkv  = (const float*)d_in[1];
    const float* bqkv  = (const float*)d_in[2];
    const float* Wproj = (const float*)d_in[3];
    const float* bproj = (const float*)d_in[4];
    float* out = (float*)d_out;

    // Workspace layout (all fp32): QKV [25088][576], Qp [24][784][64], AO [6272][192]
    float* QKV = (float*)d_ws;
    float* Qp  = QKV + (size_t)M1 * E3;           // offset 14,450,688 floats
    float* AO  = Qp + (size_t)BB * NH * NQ * HD;  // + 1,204,224 floats

    // 1) qkv = x @ W_qkv + b_qkv : (25088 x 96) @ (96 x 576)
    dim3 g1(E3 / 64, M1 / 32);   // (9, 784)
    gemm_kernel<96, 576><<<g1, 256, 0, stream>>>(x, Wqkv, bqkv, QKV);

    // 2) Q 2x2 maxpool + scale
    qpool_kernel<<<(BB * NH * NQ * HD) / 256, 256, 0, stream>>>(QKV, Qp);

    // 3) attention
    dim3 ga(25, BB * NH);        // 25 q-tiles (784 = 24*32+16), 24 (b,h) pairs
    attn_kernel<<<ga, 256, 0, stream>>>(QKV, Qp, AO);

    // 4) out = AO @ W_proj + b_proj : (6272 x 192) @ (192 x 192)
    dim3 g2(DIMO / 64, M2 / 32); // (3, 196)
    gemm_kernel<192, 192><<<g2, 256, 0, stream>>>(AO, Wproj, bproj, out);
}

// Round 2
// 270.719 us; speedup vs baseline: 1.8589x; 1.8589x over previous
//
#include <hip/hip_runtime.h>

// Problem constants
#define BB    8
#define E3    576    // 3*192
#define DIMO  192
#define NH    3
#define HD    64
#define NK    3136   // 56*56 keys per (b,h)
#define NQ    784    // 28*28 queries per (b,h)
#define M1    25088  // B*H*W
#define M2    6272   // B*NQ
#define KSPLIT 2
#define KSLICE 1568  // 49 * 32

typedef __bf16 bf16x8 __attribute__((ext_vector_type(8)));
typedef float f32x4  __attribute__((ext_vector_type(4)));

__device__ inline unsigned short f2bf(float f) {
    unsigned int u = __builtin_bit_cast(unsigned int, f);
    u += 0x7FFFu + ((u >> 16) & 1u);
    return (unsigned short)(u >> 16);
}

// ---------------------------------------------------------------------------
// fp32 GEMM (unchanged from round 1): C[M][LDB](cols bn..bn+63) = A@B + bias
// ---------------------------------------------------------------------------
template<int K, int LDB>
__launch_bounds__(256)
__global__ void gemm_kernel(const float* __restrict__ A,
                            const float* __restrict__ B,
                            const float* __restrict__ bias,
                            float* __restrict__ C) {
    constexpr int KT = 96;
    __shared__ float As[32][KT + 4];
    __shared__ float Bs[KT][64];

    const int tid = threadIdx.x;
    const int bm = blockIdx.y * 32;
    const int bn = blockIdx.x * 64;
    const int tx = tid & 15;
    const int ty = tid >> 4;

    float4 acc0 = {0.f, 0.f, 0.f, 0.f};
    float4 acc1 = {0.f, 0.f, 0.f, 0.f};

    for (int k0 = 0; k0 < K; k0 += KT) {
#pragma unroll
        for (int i = 0; i < 3; ++i) {
            int f = tid + i * 256;
            int r = f / 24, c = f % 24;
            float4 v = ((const float4*)A)[(size_t)(bm + r) * (K / 4) + (k0 / 4) + c];
            ((float4*)&As[r][0])[c] = v;
        }
#pragma unroll
        for (int i = 0; i < 6; ++i) {
            int f = tid + i * 256;
            int r = f >> 4, c = f & 15;
            float4 v = ((const float4*)B)[(size_t)(k0 + r) * (LDB / 4) + (bn >> 2) + c];
            ((float4*)&Bs[r][0])[c] = v;
        }
        __syncthreads();

#pragma unroll 8
        for (int k = 0; k < KT; ++k) {
            float a0 = As[ty][k];
            float a1 = As[ty + 16][k];
            float4 b = ((const float4*)&Bs[k][0])[tx];
            acc0.x = fmaf(a0, b.x, acc0.x);
            acc0.y = fmaf(a0, b.y, acc0.y);
            acc0.z = fmaf(a0, b.z, acc0.z);
            acc0.w = fmaf(a0, b.w, acc0.w);
            acc1.x = fmaf(a1, b.x, acc1.x);
            acc1.y = fmaf(a1, b.y, acc1.y);
            acc1.z = fmaf(a1, b.z, acc1.z);
            acc1.w = fmaf(a1, b.w, acc1.w);
        }
        __syncthreads();
    }

    float4 bb = ((const float4*)bias)[(bn >> 2) + tx];
    acc0.x += bb.x; acc0.y += bb.y; acc0.z += bb.z; acc0.w += bb.w;
    acc1.x += bb.x; acc1.y += bb.y; acc1.z += bb.z; acc1.w += bb.w;

    ((float4*)C)[(size_t)(bm + ty) * (LDB / 4) + (bn >> 2) + tx] = acc0;
    ((float4*)C)[(size_t)(bm + ty + 16) * (LDB / 4) + (bn >> 2) + tx] = acc1;
}

// ---------------------------------------------------------------------------
// Q maxpool 2x2 + scale -> bf16.  Qpb[(bh*784+q)*64 + d]
// ---------------------------------------------------------------------------
__global__ void qpool_bf16(const float* __restrict__ QKV, unsigned short* __restrict__ Qpb) {
    int idx = blockIdx.x * 256 + threadIdx.x;
    int d  = idx & 63;
    int q  = (idx >> 6) % NQ;
    int bh = idx / (64 * NQ);
    int b = bh / NH, h = bh % NH;
    int hq = q / 28, wq = q % 28;
    int col = h * 64 + d;
    const float* base = QKV + (size_t)b * NK * E3 + col;
    int r0 = (2 * hq) * 56 + 2 * wq;
    float m = base[(size_t)r0 * E3];
    m = fmaxf(m, base[(size_t)(r0 + 1) * E3]);
    m = fmaxf(m, base[(size_t)(r0 + 56) * E3]);
    m = fmaxf(m, base[(size_t)(r0 + 57) * E3]);
    Qpb[idx] = f2bf(m * 0.125f);
}

// ---------------------------------------------------------------------------
// Convert K section -> Kb bf16 [b][key][h*64+d] (stride 192),
// and V section -> Vt bf16 transposed [bh][d][key] (row stride 3136).
// One block per (64-key tile, bh).
// ---------------------------------------------------------------------------
__launch_bounds__(256)
__global__ void convert_kv(const float* __restrict__ QKV,
                           unsigned short* __restrict__ Kb,
                           unsigned short* __restrict__ Vt) {
    __shared__ unsigned short Vs[64][68];   // [key][d], row stride 136 B (8B aligned)
    const int kt = blockIdx.x * 64;
    const int bh = blockIdx.y;
    const int b = bh / NH, h = bh % NH;
    const int t = threadIdx.x;

#pragma unroll
    for (int p = 0; p < 4; ++p) {
        int idx = t + p * 256;
        int key = idx >> 4, dg = idx & 15;
        size_t row = (size_t)(b * NK + kt + key) * E3 + h * 64 + dg * 4;
        float4 kv = *(const float4*)(QKV + row + DIMO);
        float4 vv = *(const float4*)(QKV + row + 2 * DIMO);
        ushort4 kb = { f2bf(kv.x), f2bf(kv.y), f2bf(kv.z), f2bf(kv.w) };
        *(ushort4*)(Kb + (size_t)(b * NK + kt + key) * DIMO + h * 64 + dg * 4) = kb;
        ushort4 vb = { f2bf(vv.x), f2bf(vv.y), f2bf(vv.z), f2bf(vv.w) };
        *(ushort4*)(&Vs[key][dg * 4]) = vb;
    }
    __syncthreads();
#pragma unroll
    for (int p = 0; p < 16; ++p) {
        int d = p * 4 + (t >> 6);
        int key = t & 63;
        Vt[((size_t)bh * 64 + d) * NK + kt + key] = Vs[key][d];
    }
}

// ---------------------------------------------------------------------------
// MFMA attention. Grid (13 qtiles, 24 bh, 2 kslices), 256 threads = 4
// independent waves (NO barriers). Wave handles 16 queries x 1568 keys.
// Per 32-key iter: S via 4 MFMA (K,Q frags straight from global), exp in
// regs, P->LDS (bf16, padded 80B rows), 1 ds_read_b128 P-frag, 4 PV MFMA
// (Vt frags straight from global), 1 den MFMA (ones fragment).
// Partials: Pnum[ks][bh][q][64] fp32, Pden[ks][bh][q].
// ---------------------------------------------------------------------------
__launch_bounds__(256)
__global__ void attn_mfma(const unsigned short* __restrict__ Qpb,
                          const unsigned short* __restrict__ Kb,
                          const unsigned short* __restrict__ Vt,
                          float* __restrict__ Pnum,
                          float* __restrict__ Pden) {
    __shared__ unsigned short Ps[4][16][40];   // per-wave P tile [q][key], 80B rows

    const int tid  = threadIdx.x;
    const int wave = tid >> 6;
    const int lane = tid & 63;
    const int quad = lane >> 4;
    const int l16  = lane & 15;

    const int bh = blockIdx.y, b = bh / NH, h = bh % NH;
    const int qbase = blockIdx.x * 64 + wave * 16;
    const int ks = blockIdx.z;
    const int k00 = ks * KSLICE;
    const int q = qbase + l16;          // A-frag row / output column

    // Q A-fragments (2 chunks of d): A[m=l16][k=quad*8+j]
    bf16x8 qf0, qf1;
    if (q < NQ) {
        const unsigned short* qp = Qpb + ((size_t)bh * NQ + q) * HD + quad * 8;
        qf0 = *(const bf16x8*)(qp);
        qf1 = *(const bf16x8*)(qp + 32);
    } else {
        qf0 = (bf16x8)(__bf16)0.0f;
        qf1 = (bf16x8)(__bf16)0.0f;
    }

    const __bf16 one = (__bf16)1.0f;
    bf16x8 ones = { one, one, one, one, one, one, one, one };

    f32x4 zero = { 0.f, 0.f, 0.f, 0.f };
    f32x4 oacc0 = zero, oacc1 = zero, oacc2 = zero, oacc3 = zero;
    f32x4 dacc = zero;

    // Lane-fixed global bases
    const unsigned short* kbase = Kb + ((size_t)(b * NK + k00 + l16)) * DIMO + h * 64 + quad * 8;
    const unsigned short* vbase = Vt + ((size_t)bh * 64 + l16) * NK + k00 + quad * 8;
    unsigned short* myP = &Ps[wave][0][0];
    const int prd = l16 * 40 + quad * 8;   // P B-frag read offset (ushorts)

#pragma unroll 2
    for (int it = 0; it < KSLICE / 32; ++it) {
        const unsigned short* kit = kbase + (size_t)it * 32 * DIMO;

#pragma unroll
        for (int sub = 0; sub < 2; ++sub) {
            // K B-frags: B[k=d][n=key]: lane holds key=l16(+sub*16), d=quad*8+j(+32c)
            bf16x8 bk0 = *(const bf16x8*)(kit + sub * 16 * DIMO);
            bf16x8 bk1 = *(const bf16x8*)(kit + sub * 16 * DIMO + 32);
            f32x4 s = zero;
            s = __builtin_amdgcn_mfma_f32_16x16x32_bf16(qf0, bk0, s, 0, 0, 0);
            s = __builtin_amdgcn_mfma_f32_16x16x32_bf16(qf1, bk1, s, 0, 0, 0);
            // lane holds S[q=quad*4+i][key=sub*16+l16]; exp (logits bounded, no shift)
#pragma unroll
            for (int i = 0; i < 4; ++i) {
                float p = __expf(s[i]);
                myP[(quad * 4 + i) * 40 + sub * 16 + l16] = f2bf(p);
            }
        }

        // P B-frag: B[kk=key][n=q]: lane holds q=l16, keys quad*8..+7 (16B read)
        bf16x8 pb = *(const bf16x8*)(myP + prd);

        // den += ones * P  (D cols = q, all rows identical)
        dacc = __builtin_amdgcn_mfma_f32_16x16x32_bf16(ones, pb, dacc, 0, 0, 0);

        // O^T(d x q) += V^T(d x kk) * P^T(kk x q); Vt frags straight from global
        const unsigned short* vit = vbase + it * 32;
        bf16x8 va0 = *(const bf16x8*)(vit);
        bf16x8 va1 = *(const bf16x8*)(vit + (size_t)16 * NK);
        bf16x8 va2 = *(const bf16x8*)(vit + (size_t)32 * NK);
        bf16x8 va3 = *(const bf16x8*)(vit + (size_t)48 * NK);
        oacc0 = __builtin_amdgcn_mfma_f32_16x16x32_bf16(va0, pb, oacc0, 0, 0, 0);
        oacc1 = __builtin_amdgcn_mfma_f32_16x16x32_bf16(va1, pb, oacc1, 0, 0, 0);
        oacc2 = __builtin_amdgcn_mfma_f32_16x16x32_bf16(va2, pb, oacc2, 0, 0, 0);
        oacc3 = __builtin_amdgcn_mfma_f32_16x16x32_bf16(va3, pb, oacc3, 0, 0, 0);
    }

    if (q < NQ) {
        // lane holds O[q][d=dt*16+quad*4+i] for dt=0..3 (C layout: col=l16=q, row=d)
        size_t base = (size_t)ks * (24 * NQ * HD) + ((size_t)bh * NQ + q) * HD + quad * 4;
        *(f32x4*)(Pnum + base)      = oacc0;
        *(f32x4*)(Pnum + base + 16) = oacc1;
        *(f32x4*)(Pnum + base + 32) = oacc2;
        *(f32x4*)(Pnum + base + 48) = oacc3;
        if (quad == 0) Pden[ks * (24 * NQ) + bh * NQ + q] = dacc[0];
    }
}

// ---------------------------------------------------------------------------
// Combine kslice partials -> AO[(b*784+q)*192 + h*64 + d]
// ---------------------------------------------------------------------------
__global__ void combine_kernel(const float* __restrict__ Pnum,
                               const float* __restrict__ Pden,
                               float* __restrict__ AO) {
    int idx = blockIdx.x * 256 + threadIdx.x;    // over 24*784*64
    int d = idx & 63;
    int rest = idx >> 6;
    int qq = rest % NQ;
    int bh = rest / NQ;
    int b = bh / NH, h = bh % NH;
    float num = Pnum[idx] + Pnum[idx + 24 * NQ * HD];
    float den = Pden[bh * NQ + qq] + Pden[24 * NQ + bh * NQ + qq];
    AO[((size_t)b * NQ + qq) * DIMO + h * 64 + d] = num / den;
}

// ---------------------------------------------------------------------------
extern "C" void kernel_launch(void* const* d_in, const int* in_sizes, int n_in,
                              void* d_out, int out_size, void* d_ws, size_t ws_size,
                              hipStream_t stream) {
    const float* x     = (const float*)d_in[0];
    const float* Wqkv  = (const float*)d_in[1];
    const float* bqkv  = (const float*)d_in[2];
    const float* Wproj = (const float*)d_in[3];
    const float* bproj = (const float*)d_in[4];
    float* out = (float*)d_out;

    // Workspace layout (~94 MB)
    float* QKV  = (float*)d_ws;                    // 14,450,688 f
    float* Pnum = QKV + (size_t)M1 * E3;           // 2,408,448 f
    float* Pden = Pnum + (size_t)KSPLIT * 24 * NQ * HD;  // 37,632 f
    float* AO   = Pden + (size_t)KSPLIT * 24 * NQ;       // 1,204,224 f
    unsigned short* Qpb = (unsigned short*)(AO + (size_t)M2 * DIMO);  // 1,204,224 us
    unsigned short* Kb  = Qpb + (size_t)24 * NQ * HD;                 // 4,816,896 us
    unsigned short* Vt  = Kb + (size_t)BB * NK * DIMO;                // 4,816,896 us

    // 1) qkv = x @ W_qkv + b_qkv (fp32)
    gemm_kernel<96, 576><<<dim3(9, 784), 256, 0, stream>>>(x, Wqkv, bqkv, QKV);

    // 2) Q maxpool -> bf16
    qpool_bf16<<<(24 * NQ * HD) / 256, 256, 0, stream>>>(QKV, Qpb);

    // 3) K,V -> bf16 (V transposed)
    convert_kv<<<dim3(49, 24), 256, 0, stream>>>(QKV, Kb, Vt);

    // 4) MFMA attention partials
    attn_mfma<<<dim3(13, 24, KSPLIT), 256, 0, stream>>>(Qpb, Kb, Vt, Pnum, Pden);

    // 5) combine partials -> AO
    combine_kernel<<<(24 * NQ * HD) / 256, 256, 0, stream>>>(Pnum, Pden, AO);

    // 6) out = AO @ W_proj + b_proj (fp32)
    gemm_kernel<192, 192><<<dim3(3, 196), 256, 0, stream>>>(AO, Wproj, bproj, out);
}

// Round 3
// 262.659 us; speedup vs baseline: 1.9159x; 1.0307x over previous
//
#include <hip/hip_runtime.h>

// Problem constants
#define BB    8
#define E3    576    // 3*192
#define DIMO  192
#define NH    3
#define HD    64
#define NK    3136   // 56*56 keys per (b,h)
#define NQ    784    // 28*28 queries per (b,h)
#define M1    25088  // B*H*W
#define M2    6272   // B*NQ
#define KSPLIT 7
#define KSLICE 448   // 14 * 32

typedef __bf16 bf16x8 __attribute__((ext_vector_type(8)));
typedef float f32x4  __attribute__((ext_vector_type(4)));

__device__ inline unsigned short f2bf(float f) {
    unsigned int u = __builtin_bit_cast(unsigned int, f);
    u += 0x7FFFu + ((u >> 16) & 1u);
    return (unsigned short)(u >> 16);
}

// ---------------------------------------------------------------------------
// fp32 GEMM: C[M][LDB](cols bn..bn+63) = A@B + bias
// ---------------------------------------------------------------------------
template<int K, int LDB>
__launch_bounds__(256)
__global__ void gemm_kernel(const float* __restrict__ A,
                            const float* __restrict__ B,
                            const float* __restrict__ bias,
                            float* __restrict__ C) {
    constexpr int KT = 96;
    __shared__ float As[32][KT + 4];
    __shared__ float Bs[KT][64];

    const int tid = threadIdx.x;
    const int bm = blockIdx.y * 32;
    const int bn = blockIdx.x * 64;
    const int tx = tid & 15;
    const int ty = tid >> 4;

    float4 acc0 = {0.f, 0.f, 0.f, 0.f};
    float4 acc1 = {0.f, 0.f, 0.f, 0.f};

    for (int k0 = 0; k0 < K; k0 += KT) {
#pragma unroll
        for (int i = 0; i < 3; ++i) {
            int f = tid + i * 256;
            int r = f / 24, c = f % 24;
            float4 v = ((const float4*)A)[(size_t)(bm + r) * (K / 4) + (k0 / 4) + c];
            ((float4*)&As[r][0])[c] = v;
        }
#pragma unroll
        for (int i = 0; i < 6; ++i) {
            int f = tid + i * 256;
            int r = f >> 4, c = f & 15;
            float4 v = ((const float4*)B)[(size_t)(k0 + r) * (LDB / 4) + (bn >> 2) + c];
            ((float4*)&Bs[r][0])[c] = v;
        }
        __syncthreads();

#pragma unroll 8
        for (int k = 0; k < KT; ++k) {
            float a0 = As[ty][k];
            float a1 = As[ty + 16][k];
            float4 b = ((const float4*)&Bs[k][0])[tx];
            acc0.x = fmaf(a0, b.x, acc0.x);
            acc0.y = fmaf(a0, b.y, acc0.y);
            acc0.z = fmaf(a0, b.z, acc0.z);
            acc0.w = fmaf(a0, b.w, acc0.w);
            acc1.x = fmaf(a1, b.x, acc1.x);
            acc1.y = fmaf(a1, b.y, acc1.y);
            acc1.z = fmaf(a1, b.z, acc1.z);
            acc1.w = fmaf(a1, b.w, acc1.w);
        }
        __syncthreads();
    }

    float4 bb = ((const float4*)bias)[(bn >> 2) + tx];
    acc0.x += bb.x; acc0.y += bb.y; acc0.z += bb.z; acc0.w += bb.w;
    acc1.x += bb.x; acc1.y += bb.y; acc1.z += bb.z; acc1.w += bb.w;

    ((float4*)C)[(size_t)(bm + ty) * (LDB / 4) + (bn >> 2) + tx] = acc0;
    ((float4*)C)[(size_t)(bm + ty + 16) * (LDB / 4) + (bn >> 2) + tx] = acc1;
}

// ---------------------------------------------------------------------------
// Q maxpool 2x2 + scale -> bf16.  Qpb[(bh*784+q)*64 + d]
// ---------------------------------------------------------------------------
__global__ void qpool_bf16(const float* __restrict__ QKV, unsigned short* __restrict__ Qpb) {
    int idx = blockIdx.x * 256 + threadIdx.x;
    int d  = idx & 63;
    int q  = (idx >> 6) % NQ;
    int bh = idx / (64 * NQ);
    int b = bh / NH, h = bh % NH;
    int hq = q / 28, wq = q % 28;
    int col = h * 64 + d;
    const float* base = QKV + (size_t)b * NK * E3 + col;
    int r0 = (2 * hq) * 56 + 2 * wq;
    float m = base[(size_t)r0 * E3];
    m = fmaxf(m, base[(size_t)(r0 + 1) * E3]);
    m = fmaxf(m, base[(size_t)(r0 + 56) * E3]);
    m = fmaxf(m, base[(size_t)(r0 + 57) * E3]);
    Qpb[idx] = f2bf(m * 0.125f);
}

// ---------------------------------------------------------------------------
// Convert K section -> Kb bf16 [b][key][h*64+d] (stride 192),
// and V section -> Vt bf16 transposed [bh][d][key] (row stride 3136).
// ---------------------------------------------------------------------------
__launch_bounds__(256)
__global__ void convert_kv(const float* __restrict__ QKV,
                           unsigned short* __restrict__ Kb,
                           unsigned short* __restrict__ Vt) {
    __shared__ unsigned short Vs[64][68];
    const int kt = blockIdx.x * 64;
    const int bh = blockIdx.y;
    const int b = bh / NH, h = bh % NH;
    const int t = threadIdx.x;

#pragma unroll
    for (int p = 0; p < 4; ++p) {
        int idx = t + p * 256;
        int key = idx >> 4, dg = idx & 15;
        size_t row = (size_t)(b * NK + kt + key) * E3 + h * 64 + dg * 4;
        float4 kv = *(const float4*)(QKV + row + DIMO);
        float4 vv = *(const float4*)(QKV + row + 2 * DIMO);
        ushort4 kb = { f2bf(kv.x), f2bf(kv.y), f2bf(kv.z), f2bf(kv.w) };
        *(ushort4*)(Kb + (size_t)(b * NK + kt + key) * DIMO + h * 64 + dg * 4) = kb;
        ushort4 vb = { f2bf(vv.x), f2bf(vv.y), f2bf(vv.z), f2bf(vv.w) };
        *(ushort4*)(&Vs[key][dg * 4]) = vb;
    }
    __syncthreads();
#pragma unroll
    for (int p = 0; p < 16; ++p) {
        int d = p * 4 + (t >> 6);
        int key = t & 63;
        Vt[((size_t)bh * 64 + d) * NK + kt + key] = Vs[key][d];
    }
}

// ---------------------------------------------------------------------------
// MFMA attention. Grid (13 qtiles, 24 bh, 7 kslices) = 2184 blocks,
// 256 threads = 4 independent waves (no barriers). Wave: 16 q x 448 keys.
// ---------------------------------------------------------------------------
__launch_bounds__(256)
__global__ void attn_mfma(const unsigned short* __restrict__ Qpb,
                          const unsigned short* __restrict__ Kb,
                          const unsigned short* __restrict__ Vt,
                          float* __restrict__ Pnum,
                          float* __restrict__ Pden) {
    __shared__ unsigned short Ps[4][16][40];   // per-wave P tile [q][key], 80B rows

    const int tid  = threadIdx.x;
    const int wave = tid >> 6;
    const int lane = tid & 63;
    const int quad = lane >> 4;
    const int l16  = lane & 15;

    const int bh = blockIdx.y, b = bh / NH, h = bh % NH;
    const int qbase = blockIdx.x * 64 + wave * 16;
    const int ks = blockIdx.z;
    const int k00 = ks * KSLICE;
    const int q = qbase + l16;

    // Q A-fragments: A[m=l16][k=quad*8+j]
    bf16x8 qf0, qf1;
    if (q < NQ) {
        const unsigned short* qp = Qpb + ((size_t)bh * NQ + q) * HD + quad * 8;
        qf0 = *(const bf16x8*)(qp);
        qf1 = *(const bf16x8*)(qp + 32);
    } else {
        qf0 = (bf16x8)(__bf16)0.0f;
        qf1 = (bf16x8)(__bf16)0.0f;
    }

    const __bf16 one = (__bf16)1.0f;
    bf16x8 ones = { one, one, one, one, one, one, one, one };

    f32x4 zero = { 0.f, 0.f, 0.f, 0.f };
    f32x4 oacc0 = zero, oacc1 = zero, oacc2 = zero, oacc3 = zero;
    f32x4 dacc = zero;

    const unsigned short* kbase = Kb + ((size_t)(b * NK + k00 + l16)) * DIMO + h * 64 + quad * 8;
    const unsigned short* vbase = Vt + ((size_t)bh * 64 + l16) * NK + k00 + quad * 8;
    unsigned short* myP = &Ps[wave][0][0];
    const int prd = l16 * 40 + quad * 8;

#pragma unroll 2
    for (int it = 0; it < KSLICE / 32; ++it) {
        const unsigned short* kit = kbase + (size_t)it * 32 * DIMO;

#pragma unroll
        for (int sub = 0; sub < 2; ++sub) {
            bf16x8 bk0 = *(const bf16x8*)(kit + sub * 16 * DIMO);
            bf16x8 bk1 = *(const bf16x8*)(kit + sub * 16 * DIMO + 32);
            f32x4 s = zero;
            s = __builtin_amdgcn_mfma_f32_16x16x32_bf16(qf0, bk0, s, 0, 0, 0);
            s = __builtin_amdgcn_mfma_f32_16x16x32_bf16(qf1, bk1, s, 0, 0, 0);
#pragma unroll
            for (int i = 0; i < 4; ++i) {
                float p = __expf(s[i]);
                myP[(quad * 4 + i) * 40 + sub * 16 + l16] = f2bf(p);
            }
        }

        bf16x8 pb = *(const bf16x8*)(myP + prd);

        dacc = __builtin_amdgcn_mfma_f32_16x16x32_bf16(ones, pb, dacc, 0, 0, 0);

        const unsigned short* vit = vbase + it * 32;
        bf16x8 va0 = *(const bf16x8*)(vit);
        bf16x8 va1 = *(const bf16x8*)(vit + (size_t)16 * NK);
        bf16x8 va2 = *(const bf16x8*)(vit + (size_t)32 * NK);
        bf16x8 va3 = *(const bf16x8*)(vit + (size_t)48 * NK);
        oacc0 = __builtin_amdgcn_mfma_f32_16x16x32_bf16(va0, pb, oacc0, 0, 0, 0);
        oacc1 = __builtin_amdgcn_mfma_f32_16x16x32_bf16(va1, pb, oacc1, 0, 0, 0);
        oacc2 = __builtin_amdgcn_mfma_f32_16x16x32_bf16(va2, pb, oacc2, 0, 0, 0);
        oacc3 = __builtin_amdgcn_mfma_f32_16x16x32_bf16(va3, pb, oacc3, 0, 0, 0);
    }

    if (q < NQ) {
        size_t base = (size_t)ks * (24 * NQ * HD) + ((size_t)bh * NQ + q) * HD + quad * 4;
        *(f32x4*)(Pnum + base)      = oacc0;
        *(f32x4*)(Pnum + base + 16) = oacc1;
        *(f32x4*)(Pnum + base + 32) = oacc2;
        *(f32x4*)(Pnum + base + 48) = oacc3;
        if (quad == 0) Pden[ks * (24 * NQ) + bh * NQ + q] = dacc[0];
    }
}

// ---------------------------------------------------------------------------
// Combine kslice partials -> AO[(b*784+q)*192 + h*64 + d]
// ---------------------------------------------------------------------------
__global__ void combine_kernel(const float* __restrict__ Pnum,
                               const float* __restrict__ Pden,
                               float* __restrict__ AO) {
    int idx = blockIdx.x * 256 + threadIdx.x;    // over 24*784*64
    int d = idx & 63;
    int rest = idx >> 6;
    int qq = rest % NQ;
    int bh = rest / NQ;
    int b = bh / NH, h = bh % NH;
    float num = 0.f, den = 0.f;
#pragma unroll
    for (int s = 0; s < KSPLIT; ++s) {
        num += Pnum[(size_t)s * (24 * NQ * HD) + idx];
        den += Pden[s * (24 * NQ) + bh * NQ + qq];
    }
    AO[((size_t)b * NQ + qq) * DIMO + h * 64 + d] = num / den;
}

// ---------------------------------------------------------------------------
extern "C" void kernel_launch(void* const* d_in, const int* in_sizes, int n_in,
                              void* d_out, int out_size, void* d_ws, size_t ws_size,
                              hipStream_t stream) {
    const float* x     = (const float*)d_in[0];
    const float* Wqkv  = (const float*)d_in[1];
    const float* bqkv  = (const float*)d_in[2];
    const float* Wproj = (const float*)d_in[3];
    const float* bproj = (const float*)d_in[4];
    float* out = (float*)d_out;

    // Workspace layout (~84 MB). Pnum/Pden ALIAS the QKV region: QKV is dead
    // after qpool_bf16 + convert_kv complete, and stream order guarantees
    // attn_mfma runs after them. Alias region needs 8,561,280 f < 14,450,688 f.
    float* QKV  = (float*)d_ws;                          // 14,450,688 f
    float* Pnum = (float*)d_ws;                          // alias: 7*24*784*64 f
    float* Pden = Pnum + (size_t)KSPLIT * 24 * NQ * HD;  // 7*24*784 f
    float* AO   = QKV + (size_t)M1 * E3;                 // 1,204,224 f
    unsigned short* Qpb = (unsigned short*)(AO + (size_t)M2 * DIMO);  // 1,204,224 us
    unsigned short* Kb  = Qpb + (size_t)24 * NQ * HD;                 // 4,816,896 us
    unsigned short* Vt  = Kb + (size_t)BB * NK * DIMO;                // 4,816,896 us

    // 1) qkv = x @ W_qkv + b_qkv (fp32)
    gemm_kernel<96, 576><<<dim3(9, 784), 256, 0, stream>>>(x, Wqkv, bqkv, QKV);

    // 2) Q maxpool -> bf16
    qpool_bf16<<<(24 * NQ * HD) / 256, 256, 0, stream>>>(QKV, Qpb);

    // 3) K,V -> bf16 (V transposed)
    convert_kv<<<dim3(49, 24), 256, 0, stream>>>(QKV, Kb, Vt);

    // 4) MFMA attention partials (QKV region now dead; Pnum aliases it)
    attn_mfma<<<dim3(13, 24, KSPLIT), 256, 0, stream>>>(Qpb, Kb, Vt, Pnum, Pden);

    // 5) combine partials -> AO
    combine_kernel<<<(24 * NQ * HD) / 256, 256, 0, stream>>>(Pnum, Pden, AO);

    // 6) out = AO @ W_proj + b_proj (fp32)
    gemm_kernel<192, 192><<<dim3(3, 196), 256, 0, stream>>>(AO, Wproj, bproj, out);
}

// Round 4
// 148.355 us; speedup vs baseline: 3.3921x; 1.7705x over previous
//
#include <hip/hip_runtime.h>

// Problem constants
#define BB    8
#define E3    576
#define DIMO  192
#define NH    3
#define HD    64
#define NK    3136   // keys per (b,h)
#define NQ    784    // queries per (b,h)
#define M1    25088  // B*H*W
#define M2    6272   // B*NQ
#define KSPLIT 7
#define KSLICE 448   // 7 stages of 64 keys

typedef __bf16 bf16x8 __attribute__((ext_vector_type(8)));
typedef float f32x4  __attribute__((ext_vector_type(4)));

__device__ inline unsigned short f2bf(float f) {
    unsigned int u = __builtin_bit_cast(unsigned int, f);
    u += 0x7FFFu + ((u >> 16) & 1u);
    return (unsigned short)(u >> 16);
}

// ---------------------------------------------------------------------------
// W_qkv [96][576] fp32 -> Wb bf16 transposed [576][96]. Grid 18 x 256.
// ---------------------------------------------------------------------------
__global__ void wb_kernel(const float* __restrict__ Wqkv, unsigned short* __restrict__ Wb) {
    __shared__ float Ls[96][33];
    const int t = threadIdx.x;
    const int n0 = blockIdx.x * 32;
    int rr = t >> 5, c = t & 31;
#pragma unroll
    for (int rb = 0; rb < 12; ++rb) {
        int row = rb * 8 + rr;
        Ls[row][c] = Wqkv[(size_t)row * 576 + n0 + c];
    }
    __syncthreads();
    int n = t >> 3, kc = (t & 7) * 12;
#pragma unroll
    for (int j = 0; j < 12; j += 4) {
        ushort4 u = { f2bf(Ls[kc + j][n]), f2bf(Ls[kc + j + 1][n]),
                      f2bf(Ls[kc + j + 2][n]), f2bf(Ls[kc + j + 3][n]) };
        *(ushort4*)(Wb + (size_t)(n0 + n) * 96 + kc + j) = u;
    }
}

// ---------------------------------------------------------------------------
// qkv GEMM via MFMA, fused epilogue. Grid (3 ntiles, 392 mtiles), 256 thr.
// ntile 0: Q section -> Qtmp fp32 [M1][192]
// ntile 1: K section -> Kb bf16 [b*NK+key][192]
// ntile 2: V section -> Vt bf16 transposed [bh][d][key] (stride NK)
// ---------------------------------------------------------------------------
__launch_bounds__(256)
__global__ void qkv_mfma(const float* __restrict__ x,
                         const unsigned short* __restrict__ Wb,
                         const float* __restrict__ bias,
                         float* __restrict__ Qtmp,
                         unsigned short* __restrict__ Kb,
                         unsigned short* __restrict__ Vt) {
    __shared__ unsigned short xs[64 * 104];   // 64 rows x 96 bf16, 208B rows
    const int tid = threadIdx.x;
    const int wave = tid >> 6, lane = tid & 63;
    const int quad = lane >> 4, l16 = lane & 15;
    const int ntile = blockIdx.x;
    const int m0 = blockIdx.y * 64;

    // stage x tile 64x96 fp32 -> bf16 LDS
#pragma unroll
    for (int i = 0; i < 6; ++i) {
        int f = tid + i * 256;
        int r = f / 24, c4 = f % 24;
        float4 v = ((const float4*)x)[(size_t)(m0 + r) * 24 + c4];
        ushort4 u = { f2bf(v.x), f2bf(v.y), f2bf(v.z), f2bf(v.w) };
        *(ushort4*)&xs[r * 104 + c4 * 4] = u;
    }
    __syncthreads();

    f32x4 acc[12];
#pragma unroll
    for (int i = 0; i < 12; ++i) acc[i] = (f32x4){0.f, 0.f, 0.f, 0.f};

    const unsigned short* wb = Wb + (size_t)(ntile * 192 + l16) * 96 + quad * 8;
#pragma unroll
    for (int ch = 0; ch < 3; ++ch) {
        bf16x8 af = *(const bf16x8*)&xs[(wave * 16 + l16) * 104 + ch * 32 + quad * 8];
#pragma unroll
        for (int nf = 0; nf < 12; ++nf) {
            bf16x8 bfr = *(const bf16x8*)(wb + (size_t)nf * 16 * 96 + ch * 32);
            acc[nf] = __builtin_amdgcn_mfma_f32_16x16x32_bf16(af, bfr, acc[nf], 0, 0, 0);
        }
    }

    const int mbase = m0 + wave * 16 + quad * 4;
    if (ntile == 0) {
#pragma unroll
        for (int nf = 0; nf < 12; ++nf) {
            int n = nf * 16 + l16;
            float bs = bias[n];
#pragma unroll
            for (int i = 0; i < 4; ++i)
                Qtmp[(size_t)(mbase + i) * 192 + n] = acc[nf][i] + bs;
        }
    } else if (ntile == 1) {
#pragma unroll
        for (int nf = 0; nf < 12; ++nf) {
            int n = nf * 16 + l16;
            float bs = bias[192 + n];
#pragma unroll
            for (int i = 0; i < 4; ++i)
                Kb[(size_t)(mbase + i) * 192 + n] = f2bf(acc[nf][i] + bs);
        }
    } else {
        int b = m0 / NK;
        int key = mbase - b * NK;
#pragma unroll
        for (int nf = 0; nf < 12; ++nf) {
            int n = nf * 16 + l16;
            float bs = bias[384 + n];
            int hh = n >> 6, dd = n & 63;
            ushort4 u = { f2bf(acc[nf][0] + bs), f2bf(acc[nf][1] + bs),
                          f2bf(acc[nf][2] + bs), f2bf(acc[nf][3] + bs) };
            *(ushort4*)(Vt + ((size_t)((b * 3 + hh) * 64 + dd)) * NK + key) = u;
        }
    }
}

// ---------------------------------------------------------------------------
// Q maxpool 2x2 + scale -> bf16.  Qpb[(bh*784+q)*64 + d], from Qtmp [M1][192]
// ---------------------------------------------------------------------------
__global__ void qpool_bf16(const float* __restrict__ Qtmp, unsigned short* __restrict__ Qpb) {
    int idx = blockIdx.x * 256 + threadIdx.x;
    int d  = idx & 63;
    int q  = (idx >> 6) % NQ;
    int bh = idx / (64 * NQ);
    int b = bh / NH, h = bh % NH;
    int hq = q / 28, wq = q % 28;
    const float* base = Qtmp + (size_t)b * NK * 192 + h * 64 + d;
    int r0 = (2 * hq) * 56 + 2 * wq;
    float m = base[(size_t)r0 * 192];
    m = fmaxf(m, base[(size_t)(r0 + 1) * 192]);
    m = fmaxf(m, base[(size_t)(r0 + 56) * 192]);
    m = fmaxf(m, base[(size_t)(r0 + 57) * 192]);
    Qpb[idx] = f2bf(m * 0.125f);
}

// ---------------------------------------------------------------------------
// MFMA attention, LDS-staged K/V, S^T trick for cheap P transform.
// Grid (7 qtiles x 128, 24 bh, 7 kslices). Block = 4 waves x 32 q.
// Per 64-key stage: stage K/V (prefetched), S^T = K*Q^T (C-frag gives 4
// consecutive keys/lane -> 1 ds_write_b64), PV via V^T A-frags from LDS.
// ---------------------------------------------------------------------------
__launch_bounds__(256)
__global__ void attn_mfma(const unsigned short* __restrict__ Qpb,
                          const unsigned short* __restrict__ Kb,
                          const unsigned short* __restrict__ Vt,
                          float* __restrict__ Pnum,
                          float* __restrict__ Pden) {
    // row stride 88 ushorts = 176 B: 16B-aligned rows, 2-way-free banks
    __shared__ unsigned short Ks[64 * 88];
    __shared__ unsigned short Vs[64 * 88];
    __shared__ unsigned short Ps[4 * 32 * 88];

    const int tid = threadIdx.x;
    const int wave = tid >> 6, lane = tid & 63;
    const int quad = lane >> 4, l16 = lane & 15;
    const int bh = blockIdx.y, b = bh / NH, h = bh % NH;
    const int qt = blockIdx.x * 128 + wave * 32;
    const int ks = blockIdx.z, k00 = ks * KSLICE;

    // staging mapping: idx = tid + p*256 -> row = idx>>3 (0..63), chunk = idx&7
    const int srow0 = tid >> 3, sch = (tid & 7) * 8;
    const unsigned short* kg  = Kb + ((size_t)(b * NK + k00) + srow0) * DIMO + h * 64 + sch;
    const unsigned short* kg1 = kg + (size_t)32 * DIMO;
    const unsigned short* vg  = Vt + ((size_t)bh * 64 + srow0) * NK + k00 + sch;
    const unsigned short* vg1 = vg + (size_t)32 * NK;

    uint4 kp0 = *(const uint4*)kg;
    uint4 kp1 = *(const uint4*)kg1;
    uint4 vp0 = *(const uint4*)vg;
    uint4 vp1 = *(const uint4*)vg1;

    // Q B-frags (for S^T): lane holds q=l16(+16*qsub), d=quad*8+j (+32*dc)
    int qa = min(qt + l16, NQ - 1);
    int qb = min(qt + 16 + l16, NQ - 1);
    const unsigned short* qpa = Qpb + ((size_t)bh * NQ + qa) * HD + quad * 8;
    const unsigned short* qpc = Qpb + ((size_t)bh * NQ + qb) * HD + quad * 8;
    bf16x8 qf[2][2];
    qf[0][0] = *(const bf16x8*)qpa;  qf[0][1] = *(const bf16x8*)(qpa + 32);
    qf[1][0] = *(const bf16x8*)qpc;  qf[1][1] = *(const bf16x8*)(qpc + 32);

    const __bf16 one = (__bf16)1.0f;
    bf16x8 ones = { one, one, one, one, one, one, one, one };

    f32x4 on[4][2];
#pragma unroll
    for (int i = 0; i < 4; ++i)
#pragma unroll
        for (int j = 0; j < 2; ++j) on[i][j] = (f32x4){0.f, 0.f, 0.f, 0.f};
    f32x4 dn[2];
    dn[0] = (f32x4){0.f, 0.f, 0.f, 0.f};
    dn[1] = (f32x4){0.f, 0.f, 0.f, 0.f};

    unsigned short* myP = Ps + wave * 32 * 88;

    for (int s = 0; s < 7; ++s) {
        __syncthreads();   // previous stage's LDS reads complete
        *(uint4*)&Ks[srow0 * 88 + sch]        = kp0;
        *(uint4*)&Ks[(srow0 + 32) * 88 + sch] = kp1;
        *(uint4*)&Vs[srow0 * 88 + sch]        = vp0;
        *(uint4*)&Vs[(srow0 + 32) * 88 + sch] = vp1;
        __syncthreads();
        if (s < 6) {   // prefetch next stage into regs (overlaps compute)
            kp0 = *(const uint4*)(kg  + (size_t)(s + 1) * 64 * DIMO);
            kp1 = *(const uint4*)(kg1 + (size_t)(s + 1) * 64 * DIMO);
            vp0 = *(const uint4*)(vg  + (s + 1) * 64);
            vp1 = *(const uint4*)(vg1 + (s + 1) * 64);
        }

        // S^T[key][q] = K[key][d] * Q^T[d][q]; per lane: keys quad*4..+3, q=l16
#pragma unroll
        for (int ksub = 0; ksub < 4; ++ksub) {
            bf16x8 kf0 = *(const bf16x8*)&Ks[(ksub * 16 + l16) * 88 + quad * 8];
            bf16x8 kf1 = *(const bf16x8*)&Ks[(ksub * 16 + l16) * 88 + 32 + quad * 8];
#pragma unroll
            for (int qsub = 0; qsub < 2; ++qsub) {
                f32x4 sa = (f32x4){0.f, 0.f, 0.f, 0.f};
                sa = __builtin_amdgcn_mfma_f32_16x16x32_bf16(kf0, qf[qsub][0], sa, 0, 0, 0);
                sa = __builtin_amdgcn_mfma_f32_16x16x32_bf16(kf1, qf[qsub][1], sa, 0, 0, 0);
                ushort4 pw = { f2bf(__expf(sa[0])), f2bf(__expf(sa[1])),
                               f2bf(__expf(sa[2])), f2bf(__expf(sa[3])) };
                *(ushort4*)&myP[(qsub * 16 + l16) * 88 + ksub * 16 + quad * 4] = pw;
            }
        }

        // PV: O^T[d][q] += V^T[d][k] * P^T[k][q]; den += ones * P^T
#pragma unroll
        for (int k32 = 0; k32 < 2; ++k32) {
            bf16x8 pf0 = *(const bf16x8*)&myP[l16 * 88 + k32 * 32 + quad * 8];
            bf16x8 pf1 = *(const bf16x8*)&myP[(16 + l16) * 88 + k32 * 32 + quad * 8];
            dn[0] = __builtin_amdgcn_mfma_f32_16x16x32_bf16(ones, pf0, dn[0], 0, 0, 0);
            dn[1] = __builtin_amdgcn_mfma_f32_16x16x32_bf16(ones, pf1, dn[1], 0, 0, 0);
#pragma unroll
            for (int dsub = 0; dsub < 4; ++dsub) {
                bf16x8 vf = *(const bf16x8*)&Vs[(dsub * 16 + l16) * 88 + k32 * 32 + quad * 8];
                on[dsub][0] = __builtin_amdgcn_mfma_f32_16x16x32_bf16(vf, pf0, on[dsub][0], 0, 0, 0);
                on[dsub][1] = __builtin_amdgcn_mfma_f32_16x16x32_bf16(vf, pf1, on[dsub][1], 0, 0, 0);
            }
        }
    }

#pragma unroll
    for (int qsub = 0; qsub < 2; ++qsub) {
        int q = qt + qsub * 16 + l16;
        if (q < NQ) {
            size_t base = (size_t)ks * (24 * NQ * HD) + ((size_t)bh * NQ + q) * HD + quad * 4;
#pragma unroll
            for (int dsub = 0; dsub < 4; ++dsub)
                *(f32x4*)(Pnum + base + dsub * 16) = on[dsub][qsub];
            if (quad == 0) Pden[ks * (24 * NQ) + bh * NQ + q] = dn[qsub][0];
        }
    }
}

// ---------------------------------------------------------------------------
// Combine kslice partials -> AO[(b*784+q)*192 + h*64 + d]
// ---------------------------------------------------------------------------
__global__ void combine_kernel(const float* __restrict__ Pnum,
                               const float* __restrict__ Pden,
                               float* __restrict__ AO) {
    int idx = blockIdx.x * 256 + threadIdx.x;
    int d = idx & 63;
    int rest = idx >> 6;
    int qq = rest % NQ;
    int bh = rest / NQ;
    int b = bh / NH, h = bh % NH;
    float num = 0.f, den = 0.f;
#pragma unroll
    for (int s = 0; s < KSPLIT; ++s) {
        num += Pnum[(size_t)s * (24 * NQ * HD) + idx];
        den += Pden[s * (24 * NQ) + bh * NQ + qq];
    }
    AO[((size_t)b * NQ + qq) * DIMO + h * 64 + d] = num / den;
}

// ---------------------------------------------------------------------------
// fp32 GEMM (proj): C[M][LDB](cols bn..bn+63) = A@B + bias
// ---------------------------------------------------------------------------
template<int K, int LDB>
__launch_bounds__(256)
__global__ void gemm_kernel(const float* __restrict__ A,
                            const float* __restrict__ B,
                            const float* __restrict__ bias,
                            float* __restrict__ C) {
    constexpr int KT = 96;
    __shared__ float As[32][KT + 4];
    __shared__ float Bs[KT][64];

    const int tid = threadIdx.x;
    const int bm = blockIdx.y * 32;
    const int bn = blockIdx.x * 64;
    const int tx = tid & 15;
    const int ty = tid >> 4;

    float4 acc0 = {0.f, 0.f, 0.f, 0.f};
    float4 acc1 = {0.f, 0.f, 0.f, 0.f};

    for (int k0 = 0; k0 < K; k0 += KT) {
#pragma unroll
        for (int i = 0; i < 3; ++i) {
            int f = tid + i * 256;
            int r = f / 24, c = f % 24;
            float4 v = ((const float4*)A)[(size_t)(bm + r) * (K / 4) + (k0 / 4) + c];
            ((float4*)&As[r][0])[c] = v;
        }
#pragma unroll
        for (int i = 0; i < 6; ++i) {
            int f = tid + i * 256;
            int r = f >> 4, c = f & 15;
            float4 v = ((const float4*)B)[(size_t)(k0 + r) * (LDB / 4) + (bn >> 2) + c];
            ((float4*)&Bs[r][0])[c] = v;
        }
        __syncthreads();

#pragma unroll 8
        for (int k = 0; k < KT; ++k) {
            float a0 = As[ty][k];
            float a1 = As[ty + 16][k];
            float4 bb = ((const float4*)&Bs[k][0])[tx];
            acc0.x = fmaf(a0, bb.x, acc0.x);
            acc0.y = fmaf(a0, bb.y, acc0.y);
            acc0.z = fmaf(a0, bb.z, acc0.z);
            acc0.w = fmaf(a0, bb.w, acc0.w);
            acc1.x = fmaf(a1, bb.x, acc1.x);
            acc1.y = fmaf(a1, bb.y, acc1.y);
            acc1.z = fmaf(a1, bb.z, acc1.z);
            acc1.w = fmaf(a1, bb.w, acc1.w);
        }
        __syncthreads();
    }

    float4 bb = ((const float4*)bias)[(bn >> 2) + tx];
    acc0.x += bb.x; acc0.y += bb.y; acc0.z += bb.z; acc0.w += bb.w;
    acc1.x += bb.x; acc1.y += bb.y; acc1.z += bb.z; acc1.w += bb.w;

    ((float4*)C)[(size_t)(bm + ty) * (LDB / 4) + (bn >> 2) + tx] = acc0;
    ((float4*)C)[(size_t)(bm + ty + 16) * (LDB / 4) + (bn >> 2) + tx] = acc1;
}

// ---------------------------------------------------------------------------
extern "C" void kernel_launch(void* const* d_in, const int* in_sizes, int n_in,
                              void* d_out, int out_size, void* d_ws, size_t ws_size,
                              hipStream_t stream) {
    const float* x     = (const float*)d_in[0];
    const float* Wqkv  = (const float*)d_in[1];
    const float* bqkv  = (const float*)d_in[2];
    const float* Wproj = (const float*)d_in[3];
    const float* bproj = (const float*)d_in[4];
    float* out = (float*)d_out;

    // Workspace (~80.1 MB, no aliasing)
    float* Qtmp = (float*)d_ws;                              // 4,816,896 f
    float* Pnum = Qtmp + (size_t)M1 * 192;                   // 8,429,568 f
    float* Pden = Pnum + (size_t)KSPLIT * 24 * NQ * HD;      // 131,712 f
    float* AO   = Pden + (size_t)KSPLIT * 24 * NQ;           // 1,204,224 f
    unsigned short* Qpb = (unsigned short*)(AO + (size_t)M2 * DIMO);  // 1,204,224 us
    unsigned short* Kb  = Qpb + (size_t)24 * NQ * HD;                 // 4,816,896 us
    unsigned short* Vt  = Kb + (size_t)BB * NK * DIMO;                // 4,816,896 us
    unsigned short* Wb  = Vt + (size_t)24 * HD * NK;                  // 55,296 us

    // 1) W_qkv -> bf16 transposed
    wb_kernel<<<18, 256, 0, stream>>>(Wqkv, Wb);

    // 2) qkv GEMM (bf16 MFMA) with fused Q/K/V epilogue
    qkv_mfma<<<dim3(3, M1 / 64), 256, 0, stream>>>(x, Wb, bqkv, Qtmp, Kb, Vt);

    // 3) Q maxpool -> bf16
    qpool_bf16<<<(24 * NQ * HD) / 256, 256, 0, stream>>>(Qtmp, Qpb);

    // 4) MFMA attention partials
    attn_mfma<<<dim3(7, 24, KSPLIT), 256, 0, stream>>>(Qpb, Kb, Vt, Pnum, Pden);

    // 5) combine partials -> AO
    combine_kernel<<<(24 * NQ * HD) / 256, 256, 0, stream>>>(Pnum, Pden, AO);

    // 6) out = AO @ W_proj + b_proj (fp32)
    gemm_kernel<192, 192><<<dim3(3, 196), 256, 0, stream>>>(AO, Wproj, bproj, out);
}

// Round 6
// 145.893 us; speedup vs baseline: 3.4493x; 1.0169x over previous
//
#include <hip/hip_runtime.h>

// Problem constants
#define BB    8
#define E3    576
#define DIMO  192
#define NH    3
#define HD    64
#define NK    3136   // keys per (b,h)
#define NQ    784    // queries per (b,h)
#define M1    25088  // B*H*W
#define M2    6272   // B*NQ
#define KSPLIT 7
#define KSLICE 448   // 7 stages of 64 keys
#define PSTR  56     // P-tile row stride in ushorts: 112 B = 7*16 -> aligned b128

typedef __bf16 bf16x8 __attribute__((ext_vector_type(8)));
typedef float f32x4  __attribute__((ext_vector_type(4)));

__device__ inline unsigned short f2bf(float f) {
    unsigned int u = __builtin_bit_cast(unsigned int, f);
    u += 0x7FFFu + ((u >> 16) & 1u);
    return (unsigned short)(u >> 16);
}

// ---------------------------------------------------------------------------
// Weight prep: blocks 0..17: W_qkv [96][576] -> Wb bf16 [576][96] (n-major);
// blocks 18..23: W_proj [192][192] -> Wpb bf16 [192n][192k].
// ---------------------------------------------------------------------------
__global__ void wprep(const float* __restrict__ Wqkv, const float* __restrict__ Wproj,
                      unsigned short* __restrict__ Wb, unsigned short* __restrict__ Wpb) {
    __shared__ float Ls[192][33];
    const int t = threadIdx.x;
    if (blockIdx.x < 18) {
        const int n0 = blockIdx.x * 32;
        int rr = t >> 5, c = t & 31;
#pragma unroll
        for (int rb = 0; rb < 12; ++rb) {
            int row = rb * 8 + rr;
            Ls[row][c] = Wqkv[(size_t)row * 576 + n0 + c];
        }
        __syncthreads();
        int n = t >> 3, kc = (t & 7) * 12;
#pragma unroll
        for (int j = 0; j < 12; j += 4) {
            ushort4 u = { f2bf(Ls[kc + j][n]), f2bf(Ls[kc + j + 1][n]),
                          f2bf(Ls[kc + j + 2][n]), f2bf(Ls[kc + j + 3][n]) };
            *(ushort4*)(Wb + (size_t)(n0 + n) * 96 + kc + j) = u;
        }
    } else {
        const int n0 = (blockIdx.x - 18) * 32;
        int rr = t >> 5, c = t & 31;
#pragma unroll
        for (int rb = 0; rb < 24; ++rb) {
            int row = rb * 8 + rr;
            Ls[row][c] = Wproj[(size_t)row * 192 + n0 + c];
        }
        __syncthreads();
        int n = t >> 3, kc = (t & 7) * 24;
#pragma unroll
        for (int j = 0; j < 24; j += 4) {
            ushort4 u = { f2bf(Ls[kc + j][n]), f2bf(Ls[kc + j + 1][n]),
                          f2bf(Ls[kc + j + 2][n]), f2bf(Ls[kc + j + 3][n]) };
            *(ushort4*)(Wpb + (size_t)(n0 + n) * 192 + kc + j) = u;
        }
    }
}

// ---------------------------------------------------------------------------
// qkv GEMM via MFMA, fused epilogue. Grid (3 ntiles, 392 mtiles), 256 thr.
// ntile 0: Q section -> Qtmp fp32; 1: K -> Kb bf16; 2: V -> Vt bf16 transposed.
// ---------------------------------------------------------------------------
__launch_bounds__(256)
__global__ void qkv_mfma(const float* __restrict__ x,
                         const unsigned short* __restrict__ Wb,
                         const float* __restrict__ bias,
                         float* __restrict__ Qtmp,
                         unsigned short* __restrict__ Kb,
                         unsigned short* __restrict__ Vt) {
    __shared__ __attribute__((aligned(16))) unsigned short xs[64 * 104]; // 208B rows
    const int tid = threadIdx.x;
    const int wave = tid >> 6, lane = tid & 63;
    const int quad = lane >> 4, l16 = lane & 15;
    const int ntile = blockIdx.x;
    const int m0 = blockIdx.y * 64;

#pragma unroll
    for (int i = 0; i < 6; ++i) {
        int f = tid + i * 256;
        int r = f / 24, c4 = f % 24;
        float4 v = ((const float4*)x)[(size_t)(m0 + r) * 24 + c4];
        ushort4 u = { f2bf(v.x), f2bf(v.y), f2bf(v.z), f2bf(v.w) };
        *(ushort4*)&xs[r * 104 + c4 * 4] = u;
    }
    __syncthreads();

    f32x4 acc[12];
#pragma unroll
    for (int i = 0; i < 12; ++i) acc[i] = (f32x4){0.f, 0.f, 0.f, 0.f};

    const unsigned short* wb = Wb + (size_t)(ntile * 192 + l16) * 96 + quad * 8;
#pragma unroll
    for (int ch = 0; ch < 3; ++ch) {
        bf16x8 af = *(const bf16x8*)&xs[(wave * 16 + l16) * 104 + ch * 32 + quad * 8];
#pragma unroll
        for (int nf = 0; nf < 12; ++nf) {
            bf16x8 bfr = *(const bf16x8*)(wb + (size_t)nf * 16 * 96 + ch * 32);
            acc[nf] = __builtin_amdgcn_mfma_f32_16x16x32_bf16(af, bfr, acc[nf], 0, 0, 0);
        }
    }

    const int mbase = m0 + wave * 16 + quad * 4;
    if (ntile == 0) {
#pragma unroll
        for (int nf = 0; nf < 12; ++nf) {
            int n = nf * 16 + l16;
            float bs = bias[n];
#pragma unroll
            for (int i = 0; i < 4; ++i)
                Qtmp[(size_t)(mbase + i) * 192 + n] = acc[nf][i] + bs;
        }
    } else if (ntile == 1) {
#pragma unroll
        for (int nf = 0; nf < 12; ++nf) {
            int n = nf * 16 + l16;
            float bs = bias[192 + n];
#pragma unroll
            for (int i = 0; i < 4; ++i)
                Kb[(size_t)(mbase + i) * 192 + n] = f2bf(acc[nf][i] + bs);
        }
    } else {
        int b = m0 / NK;
        int key = mbase - b * NK;
#pragma unroll
        for (int nf = 0; nf < 12; ++nf) {
            int n = nf * 16 + l16;
            float bs = bias[384 + n];
            int hh = n >> 6, dd = n & 63;
            ushort4 u = { f2bf(acc[nf][0] + bs), f2bf(acc[nf][1] + bs),
                          f2bf(acc[nf][2] + bs), f2bf(acc[nf][3] + bs) };
            *(ushort4*)(Vt + ((size_t)((b * 3 + hh) * 64 + dd)) * NK + key) = u;
        }
    }
}

// ---------------------------------------------------------------------------
// Q maxpool 2x2 + scale -> bf16
// ---------------------------------------------------------------------------
__global__ void qpool_bf16(const float* __restrict__ Qtmp, unsigned short* __restrict__ Qpb) {
    int idx = blockIdx.x * 256 + threadIdx.x;
    int d  = idx & 63;
    int q  = (idx >> 6) % NQ;
    int bh = idx / (64 * NQ);
    int b = bh / NH, h = bh % NH;
    int hq = q / 28, wq = q % 28;
    const float* base = Qtmp + (size_t)b * NK * 192 + h * 64 + d;
    int r0 = (2 * hq) * 56 + 2 * wq;
    float m = base[(size_t)r0 * 192];
    m = fmaxf(m, base[(size_t)(r0 + 1) * 192]);
    m = fmaxf(m, base[(size_t)(r0 + 56) * 192]);
    m = fmaxf(m, base[(size_t)(r0 + 57) * 192]);
    Qpb[idx] = f2bf(m * 0.125f);
}

// ---------------------------------------------------------------------------
// MFMA attention. Grid (7 qtiles x 128, 24 bh, 7 kslices), 4 waves x 32q.
// 32-key halves; P rows PSTR=56 us (112 B = 7*16: b128-aligned — the round-5
// 80 B stride mis-aligned ds_read_b128 and faulted). den via VALU + shfl.
// LDS total 36.9 KB -> 4 blocks/CU.
// ---------------------------------------------------------------------------
__launch_bounds__(256)
__global__ void attn_mfma(const unsigned short* __restrict__ Qpb,
                          const unsigned short* __restrict__ Kb,
                          const unsigned short* __restrict__ Vt,
                          float* __restrict__ Pnum,
                          float* __restrict__ Pden) {
    __shared__ __attribute__((aligned(16))) unsigned short Ks[64 * 88];  // 176B rows
    __shared__ __attribute__((aligned(16))) unsigned short Vs[64 * 88];
    __shared__ __attribute__((aligned(16))) unsigned short Ps[4 * 32 * PSTR];

    const int tid = threadIdx.x;
    const int wave = tid >> 6, lane = tid & 63;
    const int quad = lane >> 4, l16 = lane & 15;
    const int bh = blockIdx.y, b = bh / NH, h = bh % NH;
    const int qt = blockIdx.x * 128 + wave * 32;
    const int ks = blockIdx.z, k00 = ks * KSLICE;

    const int srow0 = tid >> 3, sch = (tid & 7) * 8;
    const unsigned short* kg  = Kb + ((size_t)(b * NK + k00) + srow0) * DIMO + h * 64 + sch;
    const unsigned short* kg1 = kg + (size_t)32 * DIMO;
    const unsigned short* vg  = Vt + ((size_t)bh * 64 + srow0) * NK + k00 + sch;
    const unsigned short* vg1 = vg + (size_t)32 * NK;

    uint4 kp0 = *(const uint4*)kg;
    uint4 kp1 = *(const uint4*)kg1;
    uint4 vp0 = *(const uint4*)vg;
    uint4 vp1 = *(const uint4*)vg1;

    // Q B-frags: lane holds q=l16 (+16*qsub), d=quad*8+j (+32*chunk)
    int qa = min(qt + l16, NQ - 1);
    int qb = min(qt + 16 + l16, NQ - 1);
    const unsigned short* qpa = Qpb + ((size_t)bh * NQ + qa) * HD + quad * 8;
    const unsigned short* qpc = Qpb + ((size_t)bh * NQ + qb) * HD + quad * 8;
    bf16x8 qf[2][2];
    qf[0][0] = *(const bf16x8*)qpa;  qf[0][1] = *(const bf16x8*)(qpa + 32);
    qf[1][0] = *(const bf16x8*)qpc;  qf[1][1] = *(const bf16x8*)(qpc + 32);

    f32x4 on[4][2];
#pragma unroll
    for (int i = 0; i < 4; ++i)
#pragma unroll
        for (int j = 0; j < 2; ++j) on[i][j] = (f32x4){0.f, 0.f, 0.f, 0.f};
    float dden0 = 0.f, dden1 = 0.f;

    unsigned short* myP = Ps + wave * 32 * PSTR;

    for (int s = 0; s < 7; ++s) {
        __syncthreads();   // prev stage's K/V reads complete
        *(uint4*)&Ks[srow0 * 88 + sch]        = kp0;
        *(uint4*)&Ks[(srow0 + 32) * 88 + sch] = kp1;
        *(uint4*)&Vs[srow0 * 88 + sch]        = vp0;
        *(uint4*)&Vs[(srow0 + 32) * 88 + sch] = vp1;
        __syncthreads();
        if (s < 6) {   // prefetch next stage (overlaps compute)
            kp0 = *(const uint4*)(kg  + (size_t)(s + 1) * 64 * DIMO);
            kp1 = *(const uint4*)(kg1 + (size_t)(s + 1) * 64 * DIMO);
            vp0 = *(const uint4*)(vg  + (s + 1) * 64);
            vp1 = *(const uint4*)(vg1 + (s + 1) * 64);
        }

#pragma unroll
        for (int half = 0; half < 2; ++half) {
            // S^T[key][q] for keys half*32..+31: C-frag row = key, col = q
#pragma unroll
            for (int ksub = 0; ksub < 2; ++ksub) {
                const int krow = (half * 32 + ksub * 16 + l16) * 88;
                bf16x8 kf0 = *(const bf16x8*)&Ks[krow + quad * 8];
                bf16x8 kf1 = *(const bf16x8*)&Ks[krow + 32 + quad * 8];
#pragma unroll
                for (int qsub = 0; qsub < 2; ++qsub) {
                    f32x4 sa = (f32x4){0.f, 0.f, 0.f, 0.f};
                    sa = __builtin_amdgcn_mfma_f32_16x16x32_bf16(kf0, qf[qsub][0], sa, 0, 0, 0);
                    sa = __builtin_amdgcn_mfma_f32_16x16x32_bf16(kf1, qf[qsub][1], sa, 0, 0, 0);
                    float p0 = __expf(sa[0]), p1 = __expf(sa[1]);
                    float p2 = __expf(sa[2]), p3 = __expf(sa[3]);
                    if (qsub == 0) dden0 += (p0 + p1) + (p2 + p3);
                    else           dden1 += (p0 + p1) + (p2 + p3);
                    ushort4 pw = { f2bf(p0), f2bf(p1), f2bf(p2), f2bf(p3) };
                    *(ushort4*)&myP[(qsub * 16 + l16) * PSTR + ksub * 16 + quad * 4] = pw;
                }
            }
            // PV on this 32-key half (reads are 16B-aligned: PSTR*2 = 112 B)
            bf16x8 pf0 = *(const bf16x8*)&myP[l16 * PSTR + quad * 8];
            bf16x8 pf1 = *(const bf16x8*)&myP[(16 + l16) * PSTR + quad * 8];
#pragma unroll
            for (int dsub = 0; dsub < 4; ++dsub) {
                bf16x8 vf = *(const bf16x8*)&Vs[(dsub * 16 + l16) * 88 + half * 32 + quad * 8];
                on[dsub][0] = __builtin_amdgcn_mfma_f32_16x16x32_bf16(vf, pf0, on[dsub][0], 0, 0, 0);
                on[dsub][1] = __builtin_amdgcn_mfma_f32_16x16x32_bf16(vf, pf1, on[dsub][1], 0, 0, 0);
            }
        }
    }

#pragma unroll
    for (int qsub = 0; qsub < 2; ++qsub) {
        float r = (qsub == 0) ? dden0 : dden1;
        r += __shfl_xor(r, 16, 64);
        r += __shfl_xor(r, 32, 64);
        int q = qt + qsub * 16 + l16;
        if (q < NQ) {
            size_t base = (size_t)ks * (24 * NQ * HD) + ((size_t)bh * NQ + q) * HD + quad * 4;
#pragma unroll
            for (int dsub = 0; dsub < 4; ++dsub)
                *(f32x4*)(Pnum + base + dsub * 16) = on[dsub][qsub];
            if (quad == 0) Pden[ks * (24 * NQ) + bh * NQ + q] = r;
        }
    }
}

// ---------------------------------------------------------------------------
// Combine kslice partials -> AObf bf16 [(b*784+q)*192 + h*64 + d]
// ---------------------------------------------------------------------------
__global__ void combine_kernel(const float* __restrict__ Pnum,
                               const float* __restrict__ Pden,
                               unsigned short* __restrict__ AObf) {
    int idx = blockIdx.x * 256 + threadIdx.x;
    int d = idx & 63;
    int rest = idx >> 6;
    int qq = rest % NQ;
    int bh = rest / NQ;
    int b = bh / NH, h = bh % NH;
    float num = 0.f, den = 0.f;
#pragma unroll
    for (int s = 0; s < KSPLIT; ++s) {
        num += Pnum[(size_t)s * (24 * NQ * HD) + idx];
        den += Pden[s * (24 * NQ) + bh * NQ + qq];
    }
    AObf[((size_t)b * NQ + qq) * DIMO + h * 64 + d] = f2bf(num / den);
}

// ---------------------------------------------------------------------------
// proj GEMM via MFMA: out[M2][192] = AObf @ Wproj + bproj. Grid (3, 98).
// ---------------------------------------------------------------------------
__launch_bounds__(256)
__global__ void proj_mfma(const unsigned short* __restrict__ AObf,
                          const unsigned short* __restrict__ Wpb,
                          const float* __restrict__ bproj,
                          float* __restrict__ out) {
    __shared__ __attribute__((aligned(16))) unsigned short as_[64 * 200]; // 400B rows
    const int tid = threadIdx.x;
    const int wave = tid >> 6, lane = tid & 63;
    const int quad = lane >> 4, l16 = lane & 15;
    const int ntile = blockIdx.x;
    const int m0 = blockIdx.y * 64;

#pragma unroll
    for (int i = 0; i < 6; ++i) {
        int f = tid + i * 256;
        int r = f / 24, c = f % 24;
        *(uint4*)&as_[r * 200 + c * 8] = *(const uint4*)(AObf + (size_t)(m0 + r) * 192 + c * 8);
    }
    __syncthreads();

    f32x4 acc[4];
#pragma unroll
    for (int i = 0; i < 4; ++i) acc[i] = (f32x4){0.f, 0.f, 0.f, 0.f};

    const unsigned short* wp = Wpb + (size_t)(ntile * 64 + l16) * 192 + quad * 8;
#pragma unroll
    for (int ch = 0; ch < 6; ++ch) {
        bf16x8 af = *(const bf16x8*)&as_[(wave * 16 + l16) * 200 + ch * 32 + quad * 8];
#pragma unroll
        for (int nf = 0; nf < 4; ++nf) {
            bf16x8 bfr = *(const bf16x8*)(wp + (size_t)nf * 16 * 192 + ch * 32);
            acc[nf] = __builtin_amdgcn_mfma_f32_16x16x32_bf16(af, bfr, acc[nf], 0, 0, 0);
        }
    }

    const int m = m0 + wave * 16 + quad * 4;
#pragma unroll
    for (int nf = 0; nf < 4; ++nf) {
        int n = ntile * 64 + nf * 16 + l16;
        float bs = bproj[n];
#pragma unroll
        for (int i = 0; i < 4; ++i)
            out[(size_t)(m + i) * 192 + n] = acc[nf][i] + bs;
    }
}

// ---------------------------------------------------------------------------
extern "C" void kernel_launch(void* const* d_in, const int* in_sizes, int n_in,
                              void* d_out, int out_size, void* d_ws, size_t ws_size,
                              hipStream_t stream) {
    const float* x     = (const float*)d_in[0];
    const float* Wqkv  = (const float*)d_in[1];
    const float* bqkv  = (const float*)d_in[2];
    const float* Wproj = (const float*)d_in[3];
    const float* bproj = (const float*)d_in[4];
    float* out = (float*)d_out;

    // Workspace (~78 MB)
    float* Qtmp = (float*)d_ws;                              // 4,816,896 f
    float* Pnum = Qtmp + (size_t)M1 * 192;                   // 8,429,568 f
    float* Pden = Pnum + (size_t)KSPLIT * 24 * NQ * HD;      // 131,712 f
    unsigned short* AObf = (unsigned short*)(Pden + (size_t)KSPLIT * 24 * NQ);  // 1,204,224 us
    unsigned short* Qpb = AObf + (size_t)M2 * DIMO;          // 1,204,224 us
    unsigned short* Kb  = Qpb + (size_t)24 * NQ * HD;        // 4,816,896 us
    unsigned short* Vt  = Kb + (size_t)BB * NK * DIMO;       // 4,816,896 us
    unsigned short* Wb  = Vt + (size_t)24 * HD * NK;         // 55,296 us
    unsigned short* Wpb = Wb + (size_t)576 * 96;             // 36,864 us

    // 1) weight prep (both weights)
    wprep<<<24, 256, 0, stream>>>(Wqkv, Wproj, Wb, Wpb);

    // 2) qkv GEMM (bf16 MFMA) with fused Q/K/V epilogue
    qkv_mfma<<<dim3(3, M1 / 64), 256, 0, stream>>>(x, Wb, bqkv, Qtmp, Kb, Vt);

    // 3) Q maxpool -> bf16
    qpool_bf16<<<(24 * NQ * HD) / 256, 256, 0, stream>>>(Qtmp, Qpb);

    // 4) MFMA attention partials
    attn_mfma<<<dim3(7, 24, KSPLIT), 256, 0, stream>>>(Qpb, Kb, Vt, Pnum, Pden);

    // 5) combine partials -> AObf (bf16)
    combine_kernel<<<(24 * NQ * HD) / 256, 256, 0, stream>>>(Pnum, Pden, AObf);

    // 6) out = AObf @ W_proj + b_proj (bf16 MFMA)
    proj_mfma<<<dim3(3, M2 / 64), 256, 0, stream>>>(AObf, Wpb, bproj, out);
}

// Round 7
// 134.307 us; speedup vs baseline: 3.7469x; 1.0863x over previous
//
#include <hip/hip_runtime.h>

// Problem constants
#define BB    8
#define DIMO  192
#define NH    3
#define HD    64
#define NK    3136   // keys per (b,h)
#define NQ    784    // queries per (b,h)
#define M1    25088  // B*H*W
#define M2    6272   // B*NQ
#define KSPLIT 7
#define KSLICE 448   // 7 stages of 64 keys
#define PSTR  56     // P-tile row stride (ushorts): 112 B = 7*16, b128-aligned

typedef __bf16 bf16x8 __attribute__((ext_vector_type(8)));
typedef float f32x4  __attribute__((ext_vector_type(4)));

__device__ inline unsigned short f2bf(float f) {
    unsigned int u = __builtin_bit_cast(unsigned int, f);
    u += 0x7FFFu + ((u >> 16) & 1u);
    return (unsigned short)(u >> 16);
}

// ---------------------------------------------------------------------------
// Weight prep: blocks 0..17: W_qkv [96][576] -> Wb bf16 [576][96] (n-major);
// blocks 18..23: W_proj [192][192] -> Wpb bf16 [192n][192k].
// ---------------------------------------------------------------------------
__global__ void wprep(const float* __restrict__ Wqkv, const float* __restrict__ Wproj,
                      unsigned short* __restrict__ Wb, unsigned short* __restrict__ Wpb) {
    __shared__ float Ls[192][33];
    const int t = threadIdx.x;
    if (blockIdx.x < 18) {
        const int n0 = blockIdx.x * 32;
        int rr = t >> 5, c = t & 31;
#pragma unroll
        for (int rb = 0; rb < 12; ++rb) {
            int row = rb * 8 + rr;
            Ls[row][c] = Wqkv[(size_t)row * 576 + n0 + c];
        }
        __syncthreads();
        int n = t >> 3, kc = (t & 7) * 12;
#pragma unroll
        for (int j = 0; j < 12; j += 4) {
            ushort4 u = { f2bf(Ls[kc + j][n]), f2bf(Ls[kc + j + 1][n]),
                          f2bf(Ls[kc + j + 2][n]), f2bf(Ls[kc + j + 3][n]) };
            *(ushort4*)(Wb + (size_t)(n0 + n) * 96 + kc + j) = u;
        }
    } else {
        const int n0 = (blockIdx.x - 18) * 32;
        int rr = t >> 5, c = t & 31;
#pragma unroll
        for (int rb = 0; rb < 24; ++rb) {
            int row = rb * 8 + rr;
            Ls[row][c] = Wproj[(size_t)row * 192 + n0 + c];
        }
        __syncthreads();
        int n = t >> 3, kc = (t & 7) * 24;
#pragma unroll
        for (int j = 0; j < 24; j += 4) {
            ushort4 u = { f2bf(Ls[kc + j][n]), f2bf(Ls[kc + j + 1][n]),
                          f2bf(Ls[kc + j + 2][n]), f2bf(Ls[kc + j + 3][n]) };
            *(ushort4*)(Wpb + (size_t)(n0 + n) * 192 + kc + j) = u;
        }
    }
}

// ---------------------------------------------------------------------------
// Fused qkv GEMM + Q-maxpool. 1D grid of 1008 blocks:
//   bid <  392: K section, 64-row tile -> Kb bf16 [b*NK+key][192]
//   bid <  784: V section, 64-row tile -> Vt bf16 [bh][d][key]
//   bid >= 784: Q section, 112-row tile (2 image rows), rows permuted in LDS
//               as row' = 2x + dy so each 2x2 pool window = one lane's 4 C
//               accumulators -> pooled bf16 Qpb[(bh*784+q)*64+d] directly.
// ---------------------------------------------------------------------------
__launch_bounds__(256)
__global__ void qkv_fused(const float* __restrict__ x,
                          const unsigned short* __restrict__ Wb,
                          const float* __restrict__ bias,
                          unsigned short* __restrict__ Qpb,
                          unsigned short* __restrict__ Kb,
                          unsigned short* __restrict__ Vt) {
    __shared__ __attribute__((aligned(16))) unsigned short xs[112 * 104]; // 208B rows
    const int tid = threadIdx.x;
    const int wave = tid >> 6, lane = tid & 63;
    const int quad = lane >> 4, l16 = lane & 15;
    const int bid = blockIdx.x;

    if (bid < 784) {
        // ---- K / V section: 64-row tile, identical to round-6 structure ----
        const int sec = (bid < 392) ? 1 : 2;
        const int m0 = ((bid < 392) ? bid : bid - 392) * 64;
#pragma unroll
        for (int i = 0; i < 6; ++i) {
            int f = tid + i * 256;
            int r = f / 24, c4 = f % 24;
            float4 v = ((const float4*)x)[(size_t)(m0 + r) * 24 + c4];
            ushort4 u = { f2bf(v.x), f2bf(v.y), f2bf(v.z), f2bf(v.w) };
            *(ushort4*)&xs[r * 104 + c4 * 4] = u;
        }
        __syncthreads();

        f32x4 acc[12];
#pragma unroll
        for (int i = 0; i < 12; ++i) acc[i] = (f32x4){0.f, 0.f, 0.f, 0.f};

        const unsigned short* wb = Wb + (size_t)(sec * 192 + l16) * 96 + quad * 8;
#pragma unroll
        for (int ch = 0; ch < 3; ++ch) {
            bf16x8 af = *(const bf16x8*)&xs[(wave * 16 + l16) * 104 + ch * 32 + quad * 8];
#pragma unroll
            for (int nf = 0; nf < 12; ++nf) {
                bf16x8 bfr = *(const bf16x8*)(wb + (size_t)nf * 16 * 96 + ch * 32);
                acc[nf] = __builtin_amdgcn_mfma_f32_16x16x32_bf16(af, bfr, acc[nf], 0, 0, 0);
            }
        }

        const int mbase = m0 + wave * 16 + quad * 4;
        if (sec == 1) {
#pragma unroll
            for (int nf = 0; nf < 12; ++nf) {
                int n = nf * 16 + l16;
                float bs = bias[192 + n];
#pragma unroll
                for (int i = 0; i < 4; ++i)
                    Kb[(size_t)(mbase + i) * 192 + n] = f2bf(acc[nf][i] + bs);
            }
        } else {
            int b = m0 / NK;
            int key = mbase - b * NK;
#pragma unroll
            for (int nf = 0; nf < 12; ++nf) {
                int n = nf * 16 + l16;
                float bs = bias[384 + n];
                int hh = n >> 6, dd = n & 63;
                ushort4 u = { f2bf(acc[nf][0] + bs), f2bf(acc[nf][1] + bs),
                              f2bf(acc[nf][2] + bs), f2bf(acc[nf][3] + bs) };
                *(ushort4*)(Vt + ((size_t)((b * 3 + hh) * 64 + dd)) * NK + key) = u;
            }
        }
    } else {
        // ---- Q section + fused 2x2 maxpool: 112-row tile ----
        const int t = bid - 784;
        const int b = t / 28, hq = t % 28;
        const int m0 = b * NK + hq * 112;   // rows y=2hq, 2hq+1, all 56 x
#pragma unroll
        for (int i = 0; i < 11; ++i) {
            int f = tid + i * 256;
            if (f < 2688) {
                int r = f / 24, c4 = f % 24;
                float4 v = ((const float4*)x)[(size_t)(m0 + r) * 24 + c4];
                int rp = 2 * (r % 56) + (r / 56);   // row' = 2x + dy
                ushort4 u = { f2bf(v.x), f2bf(v.y), f2bf(v.z), f2bf(v.w) };
                *(ushort4*)&xs[rp * 104 + c4 * 4] = u;
            }
        }
        __syncthreads();

        f32x4 acc[7][3];
#pragma unroll
        for (int i = 0; i < 7; ++i)
#pragma unroll
            for (int j = 0; j < 3; ++j) acc[i][j] = (f32x4){0.f, 0.f, 0.f, 0.f};

        // wave w covers Q cols w*48 .. w*48+47 (3 n-frags)
        const unsigned short* wb = Wb + (size_t)(wave * 48 + l16) * 96 + quad * 8;
#pragma unroll
        for (int ch = 0; ch < 3; ++ch) {
            bf16x8 bfr[3];
#pragma unroll
            for (int jf = 0; jf < 3; ++jf)
                bfr[jf] = *(const bf16x8*)(wb + (size_t)jf * 16 * 96 + ch * 32);
#pragma unroll
            for (int mf = 0; mf < 7; ++mf) {
                bf16x8 a = *(const bf16x8*)&xs[(mf * 16 + l16) * 104 + ch * 32 + quad * 8];
#pragma unroll
                for (int jf = 0; jf < 3; ++jf)
                    acc[mf][jf] = __builtin_amdgcn_mfma_f32_16x16x32_bf16(a, bfr[jf], acc[mf][jf], 0, 0, 0);
            }
        }

        // pool: C rows 16mf+quad*4+{0..3} = permuted rows of one 2x2 window
#pragma unroll
        for (int mf = 0; mf < 7; ++mf) {
            int q = hq * 28 + mf * 4 + quad;   // pooled query index
#pragma unroll
            for (int jf = 0; jf < 3; ++jf) {
                int n = wave * 48 + jf * 16 + l16;
                float m = fmaxf(fmaxf(acc[mf][jf][0], acc[mf][jf][1]),
                                fmaxf(acc[mf][jf][2], acc[mf][jf][3]));
                m = (m + bias[n]) * 0.125f;
                int hh = n >> 6, dd = n & 63;
                Qpb[((size_t)(b * 3 + hh) * NQ + q) * 64 + dd] = f2bf(m);
            }
        }
    }
}

// ---------------------------------------------------------------------------
// MFMA attention (round-6, proven). Grid (7,24,7), 4 waves x 32q.
// ---------------------------------------------------------------------------
__launch_bounds__(256)
__global__ void attn_mfma(const unsigned short* __restrict__ Qpb,
                          const unsigned short* __restrict__ Kb,
                          const unsigned short* __restrict__ Vt,
                          float* __restrict__ Pnum,
                          float* __restrict__ Pden) {
    __shared__ __attribute__((aligned(16))) unsigned short Ks[64 * 88];  // 176B rows
    __shared__ __attribute__((aligned(16))) unsigned short Vs[64 * 88];
    __shared__ __attribute__((aligned(16))) unsigned short Ps[4 * 32 * PSTR];

    const int tid = threadIdx.x;
    const int wave = tid >> 6, lane = tid & 63;
    const int quad = lane >> 4, l16 = lane & 15;
    const int bh = blockIdx.y, b = bh / NH, h = bh % NH;
    const int qt = blockIdx.x * 128 + wave * 32;
    const int ks = blockIdx.z, k00 = ks * KSLICE;

    const int srow0 = tid >> 3, sch = (tid & 7) * 8;
    const unsigned short* kg  = Kb + ((size_t)(b * NK + k00) + srow0) * DIMO + h * 64 + sch;
    const unsigned short* kg1 = kg + (size_t)32 * DIMO;
    const unsigned short* vg  = Vt + ((size_t)bh * 64 + srow0) * NK + k00 + sch;
    const unsigned short* vg1 = vg + (size_t)32 * NK;

    uint4 kp0 = *(const uint4*)kg;
    uint4 kp1 = *(const uint4*)kg1;
    uint4 vp0 = *(const uint4*)vg;
    uint4 vp1 = *(const uint4*)vg1;

    int qa = min(qt + l16, NQ - 1);
    int qb = min(qt + 16 + l16, NQ - 1);
    const unsigned short* qpa = Qpb + ((size_t)bh * NQ + qa) * HD + quad * 8;
    const unsigned short* qpc = Qpb + ((size_t)bh * NQ + qb) * HD + quad * 8;
    bf16x8 qf[2][2];
    qf[0][0] = *(const bf16x8*)qpa;  qf[0][1] = *(const bf16x8*)(qpa + 32);
    qf[1][0] = *(const bf16x8*)qpc;  qf[1][1] = *(const bf16x8*)(qpc + 32);

    f32x4 on[4][2];
#pragma unroll
    for (int i = 0; i < 4; ++i)
#pragma unroll
        for (int j = 0; j < 2; ++j) on[i][j] = (f32x4){0.f, 0.f, 0.f, 0.f};
    float dden0 = 0.f, dden1 = 0.f;

    unsigned short* myP = Ps + wave * 32 * PSTR;

    for (int s = 0; s < 7; ++s) {
        __syncthreads();
        *(uint4*)&Ks[srow0 * 88 + sch]        = kp0;
        *(uint4*)&Ks[(srow0 + 32) * 88 + sch] = kp1;
        *(uint4*)&Vs[srow0 * 88 + sch]        = vp0;
        *(uint4*)&Vs[(srow0 + 32) * 88 + sch] = vp1;
        __syncthreads();
        if (s < 6) {
            kp0 = *(const uint4*)(kg  + (size_t)(s + 1) * 64 * DIMO);
            kp1 = *(const uint4*)(kg1 + (size_t)(s + 1) * 64 * DIMO);
            vp0 = *(const uint4*)(vg  + (s + 1) * 64);
            vp1 = *(const uint4*)(vg1 + (s + 1) * 64);
        }

#pragma unroll
        for (int half = 0; half < 2; ++half) {
#pragma unroll
            for (int ksub = 0; ksub < 2; ++ksub) {
                const int krow = (half * 32 + ksub * 16 + l16) * 88;
                bf16x8 kf0 = *(const bf16x8*)&Ks[krow + quad * 8];
                bf16x8 kf1 = *(const bf16x8*)&Ks[krow + 32 + quad * 8];
#pragma unroll
                for (int qsub = 0; qsub < 2; ++qsub) {
                    f32x4 sa = (f32x4){0.f, 0.f, 0.f, 0.f};
                    sa = __builtin_amdgcn_mfma_f32_16x16x32_bf16(kf0, qf[qsub][0], sa, 0, 0, 0);
                    sa = __builtin_amdgcn_mfma_f32_16x16x32_bf16(kf1, qf[qsub][1], sa, 0, 0, 0);
                    float p0 = __expf(sa[0]), p1 = __expf(sa[1]);
                    float p2 = __expf(sa[2]), p3 = __expf(sa[3]);
                    if (qsub == 0) dden0 += (p0 + p1) + (p2 + p3);
                    else           dden1 += (p0 + p1) + (p2 + p3);
                    ushort4 pw = { f2bf(p0), f2bf(p1), f2bf(p2), f2bf(p3) };
                    *(ushort4*)&myP[(qsub * 16 + l16) * PSTR + ksub * 16 + quad * 4] = pw;
                }
            }
            bf16x8 pf0 = *(const bf16x8*)&myP[l16 * PSTR + quad * 8];
            bf16x8 pf1 = *(const bf16x8*)&myP[(16 + l16) * PSTR + quad * 8];
#pragma unroll
            for (int dsub = 0; dsub < 4; ++dsub) {
                bf16x8 vf = *(const bf16x8*)&Vs[(dsub * 16 + l16) * 88 + half * 32 + quad * 8];
                on[dsub][0] = __builtin_amdgcn_mfma_f32_16x16x32_bf16(vf, pf0, on[dsub][0], 0, 0, 0);
                on[dsub][1] = __builtin_amdgcn_mfma_f32_16x16x32_bf16(vf, pf1, on[dsub][1], 0, 0, 0);
            }
        }
    }

#pragma unroll
    for (int qsub = 0; qsub < 2; ++qsub) {
        float r = (qsub == 0) ? dden0 : dden1;
        r += __shfl_xor(r, 16, 64);
        r += __shfl_xor(r, 32, 64);
        int q = qt + qsub * 16 + l16;
        if (q < NQ) {
            size_t base = (size_t)ks * (24 * NQ * HD) + ((size_t)bh * NQ + q) * HD + quad * 4;
#pragma unroll
            for (int dsub = 0; dsub < 4; ++dsub)
                *(f32x4*)(Pnum + base + dsub * 16) = on[dsub][qsub];
            if (quad == 0) Pden[ks * (24 * NQ) + bh * NQ + q] = r;
        }
    }
}

// ---------------------------------------------------------------------------
// Fused combine + proj. Grid 98 blocks; block = full 64x192 output tile.
// Phase 1: reduce Pnum/Pden -> bf16 A-tile in LDS. Phase 2: MFMA proj.
// ---------------------------------------------------------------------------
__launch_bounds__(256)
__global__ void proj_comb(const float* __restrict__ Pnum,
                          const float* __restrict__ Pden,
                          const unsigned short* __restrict__ Wpb,
                          const float* __restrict__ bproj,
                          float* __restrict__ out) {
    __shared__ __attribute__((aligned(16))) unsigned short as_[64 * 200]; // 400B rows
    __shared__ float rden[64][4];
    const int tid = threadIdx.x;
    const int wave = tid >> 6, lane = tid & 63;
    const int quad = lane >> 4, l16 = lane & 15;
    const int m0 = blockIdx.x * 64;

    if (tid < 192) {
        int r = tid / 3, h = tid % 3;
        int gq = m0 + r, b = gq / NQ, qq = gq - b * NQ;
        float den = 0.f;
#pragma unroll
        for (int s = 0; s < KSPLIT; ++s)
            den += Pden[s * (24 * NQ) + (b * 3 + h) * NQ + qq];
        rden[r][h] = 1.0f / den;
    }
    __syncthreads();

    {
        int r = tid >> 2, cl = tid & 3;
        int gq = m0 + r, b = gq / NQ, qq = gq - b * NQ;
#pragma unroll
        for (int i = 0; i < 12; ++i) {
            int c = cl + i * 4;            // 0..47 (f32x4 chunks of the 192 cols)
            int h = c >> 4, d = (c & 15) * 4;
            const float* p = Pnum + ((size_t)(b * 3 + h) * NQ + qq) * 64 + d;
            f32x4 num = (f32x4){0.f, 0.f, 0.f, 0.f};
#pragma unroll
            for (int s = 0; s < KSPLIT; ++s)
                num = num + *(const f32x4*)(p + (size_t)s * (24 * NQ * HD));
            float rc = rden[r][h];
            ushort4 u = { f2bf(num[0] * rc), f2bf(num[1] * rc),
                          f2bf(num[2] * rc), f2bf(num[3] * rc) };
            *(ushort4*)&as_[r * 200 + c * 4] = u;
        }
    }
    __syncthreads();

    f32x4 acc[4][3];
#pragma unroll
    for (int i = 0; i < 4; ++i)
#pragma unroll
        for (int j = 0; j < 3; ++j) acc[i][j] = (f32x4){0.f, 0.f, 0.f, 0.f};

    const unsigned short* wp = Wpb + (size_t)(wave * 48 + l16) * 192 + quad * 8;
#pragma unroll
    for (int ch = 0; ch < 6; ++ch) {
        bf16x8 bfr[3];
#pragma unroll
        for (int jf = 0; jf < 3; ++jf)
            bfr[jf] = *(const bf16x8*)(wp + (size_t)jf * 16 * 192 + ch * 32);
#pragma unroll
        for (int mf = 0; mf < 4; ++mf) {
            bf16x8 a = *(const bf16x8*)&as_[(mf * 16 + l16) * 200 + ch * 32 + quad * 8];
#pragma unroll
            for (int jf = 0; jf < 3; ++jf)
                acc[mf][jf] = __builtin_amdgcn_mfma_f32_16x16x32_bf16(a, bfr[jf], acc[mf][jf], 0, 0, 0);
        }
    }

#pragma unroll
    for (int mf = 0; mf < 4; ++mf) {
        int m = m0 + mf * 16 + quad * 4;
#pragma unroll
        for (int jf = 0; jf < 3; ++jf) {
            int n = wave * 48 + jf * 16 + l16;
            float bs = bproj[n];
#pragma unroll
            for (int i = 0; i < 4; ++i)
                out[(size_t)(m + i) * 192 + n] = acc[mf][jf][i] + bs;
        }
    }
}

// ---------------------------------------------------------------------------
extern "C" void kernel_launch(void* const* d_in, const int* in_sizes, int n_in,
                              void* d_out, int out_size, void* d_ws, size_t ws_size,
                              hipStream_t stream) {
    const float* x     = (const float*)d_in[0];
    const float* Wqkv  = (const float*)d_in[1];
    const float* bqkv  = (const float*)d_in[2];
    const float* Wproj = (const float*)d_in[3];
    const float* bproj = (const float*)d_in[4];
    float* out = (float*)d_out;

    // Workspace (~56 MB)
    float* Pnum = (float*)d_ws;                              // 7*24*784*64 f
    float* Pden = Pnum + (size_t)KSPLIT * 24 * NQ * HD;      // 7*24*784 f
    unsigned short* Qpb = (unsigned short*)(Pden + (size_t)KSPLIT * 24 * NQ); // 1,204,224 us
    unsigned short* Kb  = Qpb + (size_t)24 * NQ * HD;        // 4,816,896 us
    unsigned short* Vt  = Kb + (size_t)BB * NK * DIMO;       // 4,816,896 us
    unsigned short* Wb  = Vt + (size_t)24 * HD * NK;         // 55,296 us
    unsigned short* Wpb = Wb + (size_t)576 * 96;             // 36,864 us

    // 1) weight prep
    wprep<<<24, 256, 0, stream>>>(Wqkv, Wproj, Wb, Wpb);

    // 2) fused qkv GEMM + Q-maxpool (K:392, V:392, Q:224 blocks)
    qkv_fused<<<1008, 256, 0, stream>>>(x, Wb, bqkv, Qpb, Kb, Vt);

    // 3) MFMA attention partials
    attn_mfma<<<dim3(7, 24, KSPLIT), 256, 0, stream>>>(Qpb, Kb, Vt, Pnum, Pden);

    // 4) fused combine + proj
    proj_comb<<<98, 256, 0, stream>>>(Pnum, Pden, Wpb, bproj, out);
}

// Round 8
// 134.282 us; speedup vs baseline: 3.7476x; 1.0002x over previous
//
#include <hip/hip_runtime.h>

// Problem constants
#define BB    8
#define DIMO  192
#define NH    3
#define HD    64
#define NK    3136   // keys per (b,h)
#define NQ    784    // queries per (b,h)
#define M1    25088  // B*H*W
#define M2    6272   // B*NQ
#define KSPLIT 7
#define KSLICE 448   // 7 stages of 64 keys
#define PSTR  56     // fallback P-tile row stride (ushorts): 112 B, b128-aligned

#if __has_builtin(__builtin_amdgcn_mfma_f32_16x16x16bf16_1k)
#define HAVE_MFMA16 1
#else
#define HAVE_MFMA16 0
#endif

typedef __bf16 bf16x8 __attribute__((ext_vector_type(8)));
typedef float f32x4  __attribute__((ext_vector_type(4)));
typedef short s16x4  __attribute__((ext_vector_type(4)));

__device__ inline unsigned short f2bf(float f) {
    unsigned int u = __builtin_bit_cast(unsigned int, f);
    u += 0x7FFFu + ((u >> 16) & 1u);
    return (unsigned short)(u >> 16);
}

// ---------------------------------------------------------------------------
// Weight prep: blocks 0..17: W_qkv [96][576] -> Wb bf16 [576][96] (n-major);
// blocks 18..23: W_proj [192][192] -> Wpb bf16 [192n][192k].
// ---------------------------------------------------------------------------
__global__ void wprep(const float* __restrict__ Wqkv, const float* __restrict__ Wproj,
                      unsigned short* __restrict__ Wb, unsigned short* __restrict__ Wpb) {
    __shared__ float Ls[192][33];
    const int t = threadIdx.x;
    if (blockIdx.x < 18) {
        const int n0 = blockIdx.x * 32;
        int rr = t >> 5, c = t & 31;
#pragma unroll
        for (int rb = 0; rb < 12; ++rb) {
            int row = rb * 8 + rr;
            Ls[row][c] = Wqkv[(size_t)row * 576 + n0 + c];
        }
        __syncthreads();
        int n = t >> 3, kc = (t & 7) * 12;
#pragma unroll
        for (int j = 0; j < 12; j += 4) {
            ushort4 u = { f2bf(Ls[kc + j][n]), f2bf(Ls[kc + j + 1][n]),
                          f2bf(Ls[kc + j + 2][n]), f2bf(Ls[kc + j + 3][n]) };
            *(ushort4*)(Wb + (size_t)(n0 + n) * 96 + kc + j) = u;
        }
    } else {
        const int n0 = (blockIdx.x - 18) * 32;
        int rr = t >> 5, c = t & 31;
#pragma unroll
        for (int rb = 0; rb < 24; ++rb) {
            int row = rb * 8 + rr;
            Ls[row][c] = Wproj[(size_t)row * 192 + n0 + c];
        }
        __syncthreads();
        int n = t >> 3, kc = (t & 7) * 24;
#pragma unroll
        for (int j = 0; j < 24; j += 4) {
            ushort4 u = { f2bf(Ls[kc + j][n]), f2bf(Ls[kc + j + 1][n]),
                          f2bf(Ls[kc + j + 2][n]), f2bf(Ls[kc + j + 3][n]) };
            *(ushort4*)(Wpb + (size_t)(n0 + n) * 192 + kc + j) = u;
        }
    }
}

// ---------------------------------------------------------------------------
// Fused qkv GEMM + Q-maxpool (round-7, proven). 1008 blocks.
// ---------------------------------------------------------------------------
__launch_bounds__(256)
__global__ void qkv_fused(const float* __restrict__ x,
                          const unsigned short* __restrict__ Wb,
                          const float* __restrict__ bias,
                          unsigned short* __restrict__ Qpb,
                          unsigned short* __restrict__ Kb,
                          unsigned short* __restrict__ Vt) {
    __shared__ __attribute__((aligned(16))) unsigned short xs[112 * 104]; // 208B rows
    const int tid = threadIdx.x;
    const int wave = tid >> 6, lane = tid & 63;
    const int quad = lane >> 4, l16 = lane & 15;
    const int bid = blockIdx.x;

    if (bid < 784) {
        const int sec = (bid < 392) ? 1 : 2;
        const int m0 = ((bid < 392) ? bid : bid - 392) * 64;
#pragma unroll
        for (int i = 0; i < 6; ++i) {
            int f = tid + i * 256;
            int r = f / 24, c4 = f % 24;
            float4 v = ((const float4*)x)[(size_t)(m0 + r) * 24 + c4];
            ushort4 u = { f2bf(v.x), f2bf(v.y), f2bf(v.z), f2bf(v.w) };
            *(ushort4*)&xs[r * 104 + c4 * 4] = u;
        }
        __syncthreads();

        f32x4 acc[12];
#pragma unroll
        for (int i = 0; i < 12; ++i) acc[i] = (f32x4){0.f, 0.f, 0.f, 0.f};

        const unsigned short* wb = Wb + (size_t)(sec * 192 + l16) * 96 + quad * 8;
#pragma unroll
        for (int ch = 0; ch < 3; ++ch) {
            bf16x8 af = *(const bf16x8*)&xs[(wave * 16 + l16) * 104 + ch * 32 + quad * 8];
#pragma unroll
            for (int nf = 0; nf < 12; ++nf) {
                bf16x8 bfr = *(const bf16x8*)(wb + (size_t)nf * 16 * 96 + ch * 32);
                acc[nf] = __builtin_amdgcn_mfma_f32_16x16x32_bf16(af, bfr, acc[nf], 0, 0, 0);
            }
        }

        const int mbase = m0 + wave * 16 + quad * 4;
        if (sec == 1) {
#pragma unroll
            for (int nf = 0; nf < 12; ++nf) {
                int n = nf * 16 + l16;
                float bs = bias[192 + n];
#pragma unroll
                for (int i = 0; i < 4; ++i)
                    Kb[(size_t)(mbase + i) * 192 + n] = f2bf(acc[nf][i] + bs);
            }
        } else {
            int b = m0 / NK;
            int key = mbase - b * NK;
#pragma unroll
            for (int nf = 0; nf < 12; ++nf) {
                int n = nf * 16 + l16;
                float bs = bias[384 + n];
                int hh = n >> 6, dd = n & 63;
                ushort4 u = { f2bf(acc[nf][0] + bs), f2bf(acc[nf][1] + bs),
                              f2bf(acc[nf][2] + bs), f2bf(acc[nf][3] + bs) };
                *(ushort4*)(Vt + ((size_t)((b * 3 + hh) * 64 + dd)) * NK + key) = u;
            }
        }
    } else {
        const int t = bid - 784;
        const int b = t / 28, hq = t % 28;
        const int m0 = b * NK + hq * 112;
#pragma unroll
        for (int i = 0; i < 11; ++i) {
            int f = tid + i * 256;
            if (f < 2688) {
                int r = f / 24, c4 = f % 24;
                float4 v = ((const float4*)x)[(size_t)(m0 + r) * 24 + c4];
                int rp = 2 * (r % 56) + (r / 56);   // row' = 2x + dy
                ushort4 u = { f2bf(v.x), f2bf(v.y), f2bf(v.z), f2bf(v.w) };
                *(ushort4*)&xs[rp * 104 + c4 * 4] = u;
            }
        }
        __syncthreads();

        f32x4 acc[7][3];
#pragma unroll
        for (int i = 0; i < 7; ++i)
#pragma unroll
            for (int j = 0; j < 3; ++j) acc[i][j] = (f32x4){0.f, 0.f, 0.f, 0.f};

        const unsigned short* wb = Wb + (size_t)(wave * 48 + l16) * 96 + quad * 8;
#pragma unroll
        for (int ch = 0; ch < 3; ++ch) {
            bf16x8 bfr[3];
#pragma unroll
            for (int jf = 0; jf < 3; ++jf)
                bfr[jf] = *(const bf16x8*)(wb + (size_t)jf * 16 * 96 + ch * 32);
#pragma unroll
            for (int mf = 0; mf < 7; ++mf) {
                bf16x8 a = *(const bf16x8*)&xs[(mf * 16 + l16) * 104 + ch * 32 + quad * 8];
#pragma unroll
                for (int jf = 0; jf < 3; ++jf)
                    acc[mf][jf] = __builtin_amdgcn_mfma_f32_16x16x32_bf16(a, bfr[jf], acc[mf][jf], 0, 0, 0);
            }
        }

#pragma unroll
        for (int mf = 0; mf < 7; ++mf) {
            int q = hq * 28 + mf * 4 + quad;
#pragma unroll
            for (int jf = 0; jf < 3; ++jf) {
                int n = wave * 48 + jf * 16 + l16;
                float m = fmaxf(fmaxf(acc[mf][jf][0], acc[mf][jf][1]),
                                fmaxf(acc[mf][jf][2], acc[mf][jf][3]));
                m = (m + bias[n]) * 0.125f;
                int hh = n >> 6, dd = n & 63;
                Qpb[((size_t)(b * 3 + hh) * NQ + q) * 64 + dd] = f2bf(m);
            }
        }
    }
}

// ---------------------------------------------------------------------------
// MFMA attention. Grid (7,24,7), 4 waves x 32q. PV via K=16 MFMA whose
// B-operand layout equals the S^T C-fragment (keys quad*4+i, col q=l16) --
// P never touches LDS. LDS = Ks+Vs only (22 KB) -> higher blocks/CU.
// Fallback (no 16x16x16 builtin): round-7 Ps LDS round-trip.
// ---------------------------------------------------------------------------
__launch_bounds__(256)
__global__ void attn_mfma(const unsigned short* __restrict__ Qpb,
                          const unsigned short* __restrict__ Kb,
                          const unsigned short* __restrict__ Vt,
                          float* __restrict__ Pnum,
                          float* __restrict__ Pden) {
    __shared__ __attribute__((aligned(16))) unsigned short Ks[64 * 88];  // 176B rows
    __shared__ __attribute__((aligned(16))) unsigned short Vs[64 * 88];
#if !HAVE_MFMA16
    __shared__ __attribute__((aligned(16))) unsigned short Ps[4 * 32 * PSTR];
#endif

    const int tid = threadIdx.x;
    const int wave = tid >> 6, lane = tid & 63;
    const int quad = lane >> 4, l16 = lane & 15;
    const int bh = blockIdx.y, b = bh / NH, h = bh % NH;
    const int qt = blockIdx.x * 128 + wave * 32;
    const int ks = blockIdx.z, k00 = ks * KSLICE;

    const int srow0 = tid >> 3, sch = (tid & 7) * 8;
    const unsigned short* kg  = Kb + ((size_t)(b * NK + k00) + srow0) * DIMO + h * 64 + sch;
    const unsigned short* kg1 = kg + (size_t)32 * DIMO;
    const unsigned short* vg  = Vt + ((size_t)bh * 64 + srow0) * NK + k00 + sch;
    const unsigned short* vg1 = vg + (size_t)32 * NK;

    uint4 kp0 = *(const uint4*)kg;
    uint4 kp1 = *(const uint4*)kg1;
    uint4 vp0 = *(const uint4*)vg;
    uint4 vp1 = *(const uint4*)vg1;

    int qa = min(qt + l16, NQ - 1);
    int qb = min(qt + 16 + l16, NQ - 1);
    const unsigned short* qpa = Qpb + ((size_t)bh * NQ + qa) * HD + quad * 8;
    const unsigned short* qpc = Qpb + ((size_t)bh * NQ + qb) * HD + quad * 8;
    bf16x8 qf[2][2];
    qf[0][0] = *(const bf16x8*)qpa;  qf[0][1] = *(const bf16x8*)(qpa + 32);
    qf[1][0] = *(const bf16x8*)qpc;  qf[1][1] = *(const bf16x8*)(qpc + 32);

    f32x4 on[4][2];
#pragma unroll
    for (int i = 0; i < 4; ++i)
#pragma unroll
        for (int j = 0; j < 2; ++j) on[i][j] = (f32x4){0.f, 0.f, 0.f, 0.f};
    float dden0 = 0.f, dden1 = 0.f;

#if !HAVE_MFMA16
    unsigned short* myP = Ps + wave * 32 * PSTR;
#endif

    for (int s = 0; s < 7; ++s) {
        __syncthreads();
        *(uint4*)&Ks[srow0 * 88 + sch]        = kp0;
        *(uint4*)&Ks[(srow0 + 32) * 88 + sch] = kp1;
        *(uint4*)&Vs[srow0 * 88 + sch]        = vp0;
        *(uint4*)&Vs[(srow0 + 32) * 88 + sch] = vp1;
        __syncthreads();
        if (s < 6) {
            kp0 = *(const uint4*)(kg  + (size_t)(s + 1) * 64 * DIMO);
            kp1 = *(const uint4*)(kg1 + (size_t)(s + 1) * 64 * DIMO);
            vp0 = *(const uint4*)(vg  + (s + 1) * 64);
            vp1 = *(const uint4*)(vg1 + (s + 1) * 64);
        }

#if HAVE_MFMA16
        // 4 groups of 16 keys; P stays in registers (C-frag == K=16 B-frag)
#pragma unroll
        for (int g = 0; g < 4; ++g) {
            const int krow = (g * 16 + l16) * 88;
            bf16x8 kf0 = *(const bf16x8*)&Ks[krow + quad * 8];
            bf16x8 kf1 = *(const bf16x8*)&Ks[krow + 32 + quad * 8];
            s16x4 vf[4];
#pragma unroll
            for (int dsub = 0; dsub < 4; ++dsub)
                vf[dsub] = *(const s16x4*)&Vs[(dsub * 16 + l16) * 88 + g * 16 + quad * 4];
#pragma unroll
            for (int qsub = 0; qsub < 2; ++qsub) {
                f32x4 sa = (f32x4){0.f, 0.f, 0.f, 0.f};
                sa = __builtin_amdgcn_mfma_f32_16x16x32_bf16(kf0, qf[qsub][0], sa, 0, 0, 0);
                sa = __builtin_amdgcn_mfma_f32_16x16x32_bf16(kf1, qf[qsub][1], sa, 0, 0, 0);
                float p0 = __expf(sa[0]), p1 = __expf(sa[1]);
                float p2 = __expf(sa[2]), p3 = __expf(sa[3]);
                if (qsub == 0) dden0 += (p0 + p1) + (p2 + p3);
                else           dden1 += (p0 + p1) + (p2 + p3);
                s16x4 pb = { (short)f2bf(p0), (short)f2bf(p1),
                             (short)f2bf(p2), (short)f2bf(p3) };
#pragma unroll
                for (int dsub = 0; dsub < 4; ++dsub)
                    on[dsub][qsub] = __builtin_amdgcn_mfma_f32_16x16x16bf16_1k(
                        vf[dsub], pb, on[dsub][qsub], 0, 0, 0);
            }
        }
#else
#pragma unroll
        for (int half = 0; half < 2; ++half) {
#pragma unroll
            for (int ksub = 0; ksub < 2; ++ksub) {
                const int krow = (half * 32 + ksub * 16 + l16) * 88;
                bf16x8 kf0 = *(const bf16x8*)&Ks[krow + quad * 8];
                bf16x8 kf1 = *(const bf16x8*)&Ks[krow + 32 + quad * 8];
#pragma unroll
                for (int qsub = 0; qsub < 2; ++qsub) {
                    f32x4 sa = (f32x4){0.f, 0.f, 0.f, 0.f};
                    sa = __builtin_amdgcn_mfma_f32_16x16x32_bf16(kf0, qf[qsub][0], sa, 0, 0, 0);
                    sa = __builtin_amdgcn_mfma_f32_16x16x32_bf16(kf1, qf[qsub][1], sa, 0, 0, 0);
                    float p0 = __expf(sa[0]), p1 = __expf(sa[1]);
                    float p2 = __expf(sa[2]), p3 = __expf(sa[3]);
                    if (qsub == 0) dden0 += (p0 + p1) + (p2 + p3);
                    else           dden1 += (p0 + p1) + (p2 + p3);
                    ushort4 pw = { f2bf(p0), f2bf(p1), f2bf(p2), f2bf(p3) };
                    *(ushort4*)&myP[(qsub * 16 + l16) * PSTR + ksub * 16 + quad * 4] = pw;
                }
            }
            bf16x8 pf0 = *(const bf16x8*)&myP[l16 * PSTR + quad * 8];
            bf16x8 pf1 = *(const bf16x8*)&myP[(16 + l16) * PSTR + quad * 8];
#pragma unroll
            for (int dsub = 0; dsub < 4; ++dsub) {
                bf16x8 vf = *(const bf16x8*)&Vs[(dsub * 16 + l16) * 88 + half * 32 + quad * 8];
                on[dsub][0] = __builtin_amdgcn_mfma_f32_16x16x32_bf16(vf, pf0, on[dsub][0], 0, 0, 0);
                on[dsub][1] = __builtin_amdgcn_mfma_f32_16x16x32_bf16(vf, pf1, on[dsub][1], 0, 0, 0);
            }
        }
#endif
    }

#pragma unroll
    for (int qsub = 0; qsub < 2; ++qsub) {
        float r = (qsub == 0) ? dden0 : dden1;
        r += __shfl_xor(r, 16, 64);
        r += __shfl_xor(r, 32, 64);
        int q = qt + qsub * 16 + l16;
        if (q < NQ) {
            size_t base = (size_t)ks * (24 * NQ * HD) + ((size_t)bh * NQ + q) * HD + quad * 4;
#pragma unroll
            for (int dsub = 0; dsub < 4; ++dsub)
                *(f32x4*)(Pnum + base + dsub * 16) = on[dsub][qsub];
            if (quad == 0) Pden[ks * (24 * NQ) + bh * NQ + q] = r;
        }
    }
}

// ---------------------------------------------------------------------------
// Fused combine + proj. Grid 392 blocks; block = 16x192 output tile.
// ---------------------------------------------------------------------------
__launch_bounds__(256)
__global__ void proj_comb(const float* __restrict__ Pnum,
                          const float* __restrict__ Pden,
                          const unsigned short* __restrict__ Wpb,
                          const float* __restrict__ bproj,
                          float* __restrict__ out) {
    __shared__ __attribute__((aligned(16))) unsigned short as_[16 * 200]; // 400B rows
    __shared__ float rden[16][4];
    const int tid = threadIdx.x;
    const int wave = tid >> 6, lane = tid & 63;
    const int quad = lane >> 4, l16 = lane & 15;
    const int m0 = blockIdx.x * 16;

    if (tid < 48) {
        int r = tid / 3, h = tid % 3;
        int gq = m0 + r, b = gq / NQ, qq = gq - b * NQ;
        float den = 0.f;
#pragma unroll
        for (int s = 0; s < KSPLIT; ++s)
            den += Pden[s * (24 * NQ) + (b * 3 + h) * NQ + qq];
        rden[r][h] = 1.0f / den;
    }
    __syncthreads();

    {
        int r = tid >> 4, cl = tid & 15;
        int gq = m0 + r, b = gq / NQ, qq = gq - b * NQ;
#pragma unroll
        for (int i = 0; i < 3; ++i) {
            int c = cl + i * 16;           // 0..47 (f32x4 chunks of the 192 cols)
            int h = c >> 4, d = (c & 15) * 4;
            const float* p = Pnum + ((size_t)(b * 3 + h) * NQ + qq) * 64 + d;
            f32x4 num = (f32x4){0.f, 0.f, 0.f, 0.f};
#pragma unroll
            for (int s = 0; s < KSPLIT; ++s)
                num = num + *(const f32x4*)(p + (size_t)s * (24 * NQ * HD));
            float rc = rden[r][h];
            ushort4 u = { f2bf(num[0] * rc), f2bf(num[1] * rc),
                          f2bf(num[2] * rc), f2bf(num[3] * rc) };
            *(ushort4*)&as_[r * 200 + c * 4] = u;
        }
    }
    __syncthreads();

    f32x4 acc[3];
#pragma unroll
    for (int j = 0; j < 3; ++j) acc[j] = (f32x4){0.f, 0.f, 0.f, 0.f};

    const unsigned short* wp = Wpb + (size_t)(wave * 48 + l16) * 192 + quad * 8;
#pragma unroll
    for (int ch = 0; ch < 6; ++ch) {
        bf16x8 a = *(const bf16x8*)&as_[l16 * 200 + ch * 32 + quad * 8];
#pragma unroll
        for (int jf = 0; jf < 3; ++jf) {
            bf16x8 bfr = *(const bf16x8*)(wp + (size_t)jf * 16 * 192 + ch * 32);
            acc[jf] = __builtin_amdgcn_mfma_f32_16x16x32_bf16(a, bfr, acc[jf], 0, 0, 0);
        }
    }

    const int m = m0 + quad * 4;
#pragma unroll
    for (int jf = 0; jf < 3; ++jf) {
        int n = wave * 48 + jf * 16 + l16;
        float bs = bproj[n];
#pragma unroll
        for (int i = 0; i < 4; ++i)
            out[(size_t)(m + i) * 192 + n] = acc[jf][i] + bs;
    }
}

// ---------------------------------------------------------------------------
extern "C" void kernel_launch(void* const* d_in, const int* in_sizes, int n_in,
                              void* d_out, int out_size, void* d_ws, size_t ws_size,
                              hipStream_t stream) {
    const float* x     = (const float*)d_in[0];
    const float* Wqkv  = (const float*)d_in[1];
    const float* bqkv  = (const float*)d_in[2];
    const float* Wproj = (const float*)d_in[3];
    const float* bproj = (const float*)d_in[4];
    float* out = (float*)d_out;

    // Workspace (~56 MB)
    float* Pnum = (float*)d_ws;                              // 7*24*784*64 f
    float* Pden = Pnum + (size_t)KSPLIT * 24 * NQ * HD;      // 7*24*784 f
    unsigned short* Qpb = (unsigned short*)(Pden + (size_t)KSPLIT * 24 * NQ); // 1,204,224 us
    unsigned short* Kb  = Qpb + (size_t)24 * NQ * HD;        // 4,816,896 us
    unsigned short* Vt  = Kb + (size_t)BB * NK * DIMO;       // 4,816,896 us
    unsigned short* Wb  = Vt + (size_t)24 * HD * NK;         // 55,296 us
    unsigned short* Wpb = Wb + (size_t)576 * 96;             // 36,864 us

    // 1) weight prep
    wprep<<<24, 256, 0, stream>>>(Wqkv, Wproj, Wb, Wpb);

    // 2) fused qkv GEMM + Q-maxpool (K:392, V:392, Q:224 blocks)
    qkv_fused<<<1008, 256, 0, stream>>>(x, Wb, bqkv, Qpb, Kb, Vt);

    // 3) MFMA attention partials
    attn_mfma<<<dim3(7, 24, KSPLIT), 256, 0, stream>>>(Qpb, Kb, Vt, Pnum, Pden);

    // 4) fused combine + proj (16-row tiles: 4x more blocks than round 7)
    proj_comb<<<392, 256, 0, stream>>>(Pnum, Pden, Wpb, bproj, out);
}